// Round 1
// baseline (2035.713 us; speedup 1.0000x reference)
//
#include <hip/hip_runtime.h>
#include <cstddef>

// ---------------- problem constants ----------------
constexpr int Bfull = 512;
constexpr int CHUNK = 128;          // batch chunk to bound workspace
constexpr int NCHUNK = Bfull / CHUNK;
constexpr int F = 4, O = 10, H = 128, W = 128;

// workspace layout (floats), per-chunk buffers
constexpr size_t T_ELEMS  = (size_t)CHUNK * F * H * W;        // 8,388,608
constexpr size_t C1_ELEMS = (size_t)CHUNK * 32 * 64 * 64;     // 16,777,216
constexpr size_t P1_ELEMS = (size_t)CHUNK * 32 * 31 * 31;     // 3,936,256
constexpr size_t C2_ELEMS = (size_t)CHUNK * 64 * 31 * 31;     // 7,872,512
constexpr size_t P2_ELEMS = (size_t)CHUNK * 64 * 15 * 15;     // 1,843,200
constexpr size_t C3_ELEMS = (size_t)CHUNK * 128 * 15 * 15;    // 3,686,400
constexpr size_t FEAT_ELEMS = (size_t)Bfull * 128;            // 65,536

// ---------------- rasterize ----------------
// one block per (b_local, f); replays the reference write order per pixel
__global__ __launch_bounds__(256) void rasterize_k(const int* __restrict__ x,
                                                   float* __restrict__ t, int b0) {
    int bf = blockIdx.x;              // 0..CHUNK*F-1
    int b_l = bf / F, f = bf % F;
    int b = b0 + b_l;
    __shared__ int pts[O][2];
    __shared__ int ka[O - 1], kb[O - 1];
    if (threadIdx.x < O * 2)
        ((int*)pts)[threadIdx.x] = x[((size_t)(b * F + f) * O) * 2 + threadIdx.x];
    __syncthreads();
    if (threadIdx.x < O - 1) {
        int k = threadIdx.x;
        int a  = (pts[k][0] + 64) % 127;   // operands positive (34..94): identity
        int bb = (64 - pts[k][1]) % 127;
        ka[k] = a; kb[k] = bb;
    }
    __syncthreads();
    int dX = 64 + pts[O - 1][0];
    int dY = 64 - pts[O - 1][1];
    int loX = dX >= 64 ? 64 : dX + 1, hiX = dX >= 64 ? dX - 1 : 64;
    int loY = dY >= 64 ? 64 : dY + 1, hiY = dY >= 64 ? dY - 1 : 64;
    float* tp = t + (size_t)bf * (H * W);
    for (int i = threadIdx.x; i < H * W; i += 256) {
        int y = i >> 7, xx = i & 127;
        bool mX = (xx >= loX) && (xx <= hiX);
        bool mY = (y >= loY) && (y <= hiY);
        bool path = (mX && y == 64) || (mY && xx == dX);
        float v = path ? -1.f : 0.f;
        if (y >= 63 && y <= 65 && xx >= 63 && xx <= 65) v = 0.5f;
        if (y == 64 && xx == 64) v = 1.f;
        #pragma unroll
        for (int k = 0; k < O - 1; ++k) {
            int a = ka[k], bb = kb[k];
            if (y >= bb - 1 && y <= bb + 1 && xx >= a - 1 && xx <= a + 1) v = 0.5f;
            if (y == bb && xx == a) v = 1.f;
        }
        tp[i] = v;
    }
}

// ---------------- conv1: 4->32, k7 s2 p3, + bias + relu ----------------
// block = (16x16 output tile, one b); thread holds all 32 oc accumulators
__global__ __launch_bounds__(256) void conv1_k(const float* __restrict__ t,
                                               const float* __restrict__ w1,
                                               const float* __restrict__ b1,
                                               float* __restrict__ c1) {
    __shared__ float sIn[4][37][37];
    __shared__ float sW[7][7][4][32];
    __shared__ float sB[32];
    int b_l = blockIdx.y;
    int tile = blockIdx.x;                      // 0..15
    int oy0 = (tile >> 2) * 16, ox0 = (tile & 3) * 16;
    int iy0 = oy0 * 2 - 3, ix0 = ox0 * 2 - 3;
    int tid = threadIdx.x;
    for (int idx = tid; idx < 4 * 37 * 37; idx += 256) {
        int ic = idx / (37 * 37); int rem = idx % (37 * 37);
        int r = rem / 37, c = rem % 37;
        int iy = iy0 + r, ix = ix0 + c;
        float v = 0.f;
        if (iy >= 0 && iy < 128 && ix >= 0 && ix < 128)
            v = t[(((size_t)b_l * 4 + ic) * 128 + iy) * 128 + ix];
        sIn[ic][r][c] = v;
    }
    for (int idx = tid; idx < 6272; idx += 256) {
        int oc = idx & 31; int t2 = idx >> 5;
        int ic = t2 & 3;  int t3 = t2 >> 2;
        int kx = t3 % 7,  ky = t3 / 7;
        sW[ky][kx][ic][oc] = w1[((oc * 4 + ic) * 7 + ky) * 7 + kx];
    }
    if (tid < 32) sB[tid] = b1[tid];
    __syncthreads();
    int ty = tid >> 4, tx = tid & 15;
    float acc[32];
    #pragma unroll
    for (int oc = 0; oc < 32; ++oc) acc[oc] = sB[oc];
    for (int ic = 0; ic < 4; ++ic)
        for (int ky = 0; ky < 7; ++ky)
            #pragma unroll
            for (int kx = 0; kx < 7; ++kx) {
                float v = sIn[ic][2 * ty + ky][2 * tx + kx];
                const float* wp = sW[ky][kx][ic];
                #pragma unroll
                for (int oc = 0; oc < 32; ++oc) acc[oc] = fmaf(v, wp[oc], acc[oc]);
            }
    int oy = oy0 + ty, ox = ox0 + tx;
    float* outp = c1 + (size_t)b_l * 32 * 64 * 64 + (size_t)oy * 64 + ox;
    #pragma unroll
    for (int oc = 0; oc < 32; ++oc)
        outp[(size_t)oc * 64 * 64] = fmaxf(acc[oc], 0.f);
}

// ---------------- pool1: 3x3 s2 on [*,32,64,64] -> [*,32,31,31] ----------------
__global__ __launch_bounds__(256) void pool1_k(const float* __restrict__ c1,
                                               float* __restrict__ p1) {
    int idx = blockIdx.x * 256 + threadIdx.x;
    constexpr int total = CHUNK * 32 * 31 * 31;
    if (idx >= total) return;
    int px = idx % 31; int t1 = idx / 31;
    int py = t1 % 31;  int ch = t1 / 31;          // ch = b_l*32+oc
    const float* base = c1 + (size_t)ch * 64 * 64;
    float m = -INFINITY;
    #pragma unroll
    for (int dy = 0; dy < 3; ++dy)
        #pragma unroll
        for (int dx = 0; dx < 3; ++dx)
            m = fmaxf(m, base[(2 * py + dy) * 64 + 2 * px + dx]);
    p1[idx] = m;
}

// ---------------- conv2: 32->64, k5 s1 p2, + bias + relu ----------------
// block: (b_l, oc-group of 32, col-tile of 16); thread = 16x16, covers rows ty and ty+16
__global__ __launch_bounds__(256) void conv2_k(const float* __restrict__ p1,
                                               const float* __restrict__ w2,
                                               const float* __restrict__ b2,
                                               float* __restrict__ c2) {
    __shared__ float sIn[8][36][20];
    __shared__ float sW[5][5][8][32];
    int b_l = blockIdx.y;
    int og = blockIdx.x >> 1;        // 0/1
    int ct = blockIdx.x & 1;         // 0/1
    int oc0 = og * 32;
    int ox0 = ct * 16;
    int tid = threadIdx.x;
    int ty = tid >> 4, tx = tid & 15;
    float acc[64];
    #pragma unroll
    for (int i = 0; i < 64; ++i) acc[i] = 0.f;
    for (int icc = 0; icc < 4; ++icc) {
        int ic0 = icc * 8;
        for (int idx = tid; idx < 8 * 36 * 20; idx += 256) {
            int c = idx % 20; int t1 = idx / 20;
            int r = t1 % 36;  int ic = t1 / 36;
            int iy = r - 2, ix = ox0 + c - 2;
            float v = 0.f;
            if (iy >= 0 && iy < 31 && ix >= 0 && ix < 31)
                v = p1[(((size_t)b_l * 32 + ic0 + ic) * 31 + iy) * 31 + ix];
            sIn[ic][r][c] = v;
        }
        for (int idx = tid; idx < 5 * 5 * 8 * 32; idx += 256) {
            int oc = idx & 31; int t1 = idx >> 5;
            int ic = t1 & 7;   int t2 = t1 >> 3;
            int kx = t2 % 5,   ky = t2 / 5;
            sW[ky][kx][ic][oc] = w2[(((size_t)(oc0 + oc) * 32 + ic0 + ic) * 5 + ky) * 5 + kx];
        }
        __syncthreads();
        for (int ic = 0; ic < 8; ++ic)
            for (int ky = 0; ky < 5; ++ky)
                #pragma unroll
                for (int kx = 0; kx < 5; ++kx) {
                    float vA = sIn[ic][ty + ky][tx + kx];
                    float vB = sIn[ic][ty + 16 + ky][tx + kx];
                    const float* wp = sW[ky][kx][ic];
                    #pragma unroll
                    for (int oc = 0; oc < 32; ++oc) {
                        float w = wp[oc];
                        acc[oc]      = fmaf(vA, w, acc[oc]);
                        acc[32 + oc] = fmaf(vB, w, acc[32 + oc]);
                    }
                }
        __syncthreads();
    }
    int ox = ox0 + tx;
    if (ox < 31) {
        #pragma unroll
        for (int half = 0; half < 2; ++half) {
            int oy = ty + half * 16;
            if (oy < 31) {
                float* outp = c2 + ((size_t)b_l * 64 + oc0) * 31 * 31 + (size_t)oy * 31 + ox;
                #pragma unroll
                for (int oc = 0; oc < 32; ++oc)
                    outp[(size_t)oc * 31 * 31] = fmaxf(acc[half * 32 + oc] + b2[oc0 + oc], 0.f);
            }
        }
    }
}

// ---------------- pool2: 2x2 s2 on [*,64,31,31] -> [*,64,15,15] ----------------
__global__ __launch_bounds__(256) void pool2_k(const float* __restrict__ c2,
                                               float* __restrict__ p2) {
    int idx = blockIdx.x * 256 + threadIdx.x;
    constexpr int total = CHUNK * 64 * 15 * 15;
    if (idx >= total) return;
    int px = idx % 15; int t1 = idx / 15;
    int py = t1 % 15;  int ch = t1 / 15;
    const float* base = c2 + (size_t)ch * 31 * 31;
    float m = fmaxf(fmaxf(base[(2 * py) * 31 + 2 * px],     base[(2 * py) * 31 + 2 * px + 1]),
                    fmaxf(base[(2 * py + 1) * 31 + 2 * px], base[(2 * py + 1) * 31 + 2 * px + 1]));
    p2[idx] = m;
}

// ---------------- conv3: 64->128, k3 s1 p1, + bias + relu ----------------
// block: (b_l, oc-group of 32); thread < 225 -> one spatial pos, 32 oc accs
__global__ __launch_bounds__(256) void conv3_k(const float* __restrict__ p2,
                                               const float* __restrict__ w3,
                                               const float* __restrict__ b3,
                                               float* __restrict__ c3) {
    __shared__ float sIn[16][17][17];
    __shared__ float sW[3][3][16][32];
    int b_l = blockIdx.y;
    int oc0 = blockIdx.x * 32;
    int tid = threadIdx.x;
    int oy = tid / 15, ox = tid % 15;
    bool act = tid < 225;
    float acc[32];
    #pragma unroll
    for (int i = 0; i < 32; ++i) acc[i] = 0.f;
    for (int icc = 0; icc < 4; ++icc) {
        int ic0 = icc * 16;
        for (int idx = tid; idx < 16 * 17 * 17; idx += 256) {
            int c = idx % 17; int t1 = idx / 17;
            int r = t1 % 17;  int ic = t1 / 17;
            int iy = r - 1, ix = c - 1;
            float v = 0.f;
            if (iy >= 0 && iy < 15 && ix >= 0 && ix < 15)
                v = p2[(((size_t)b_l * 64 + ic0 + ic) * 15 + iy) * 15 + ix];
            sIn[ic][r][c] = v;
        }
        for (int idx = tid; idx < 3 * 3 * 16 * 32; idx += 256) {
            int oc = idx & 31; int t1 = idx >> 5;
            int ic = t1 & 15;  int t2 = t1 >> 4;
            int kx = t2 % 3,   ky = t2 / 3;
            sW[ky][kx][ic][oc] = w3[(((size_t)(oc0 + oc) * 64 + ic0 + ic) * 3 + ky) * 3 + kx];
        }
        __syncthreads();
        if (act) {
            for (int ic = 0; ic < 16; ++ic)
                #pragma unroll
                for (int ky = 0; ky < 3; ++ky)
                    #pragma unroll
                    for (int kx = 0; kx < 3; ++kx) {
                        float v = sIn[ic][oy + ky][ox + kx];
                        const float* wp = sW[ky][kx][ic];
                        #pragma unroll
                        for (int oc = 0; oc < 32; ++oc) acc[oc] = fmaf(v, wp[oc], acc[oc]);
                    }
        }
        __syncthreads();
    }
    if (act) {
        float* outp = c3 + ((size_t)b_l * 128 + oc0) * 225 + oy * 15 + ox;
        #pragma unroll
        for (int oc = 0; oc < 32; ++oc)
            outp[(size_t)oc * 225] = fmaxf(acc[oc] + b3[oc0 + oc], 0.f);
    }
}

// ---------------- pool3 (2x2 s2, 15->7) + spatial mean -> feat[b][oc] ----------------
__global__ __launch_bounds__(256) void pool3mean_k(const float* __restrict__ c3,
                                                   float* __restrict__ feat, int b0) {
    int idx = blockIdx.x * 256 + threadIdx.x;
    if (idx >= CHUNK * 128) return;
    int oc = idx & 127, b_l = idx >> 7;
    const float* base = c3 + (size_t)idx * 225;
    float s = 0.f;
    #pragma unroll
    for (int py = 0; py < 7; ++py)
        #pragma unroll
        for (int px = 0; px < 7; ++px) {
            float m = fmaxf(fmaxf(base[(2 * py) * 15 + 2 * px],     base[(2 * py) * 15 + 2 * px + 1]),
                            fmaxf(base[(2 * py + 1) * 15 + 2 * px], base[(2 * py + 1) * 15 + 2 * px + 1]));
            s += m;
        }
    feat[(size_t)(b0 + b_l) * 128 + oc] = s * (1.f / 49.f);
}

// ---------------- fc1 (relu) + fc2 ----------------
__global__ __launch_bounds__(128) void fc_k(const float* __restrict__ feat,
                                            const float* __restrict__ fw1,
                                            const float* __restrict__ fb1,
                                            const float* __restrict__ fw2,
                                            const float* __restrict__ fb2,
                                            float* __restrict__ out) {
    __shared__ float sF[128];
    __shared__ float sH[128];
    int b = blockIdx.x, tid = threadIdx.x;
    sF[tid] = feat[(size_t)b * 128 + tid];
    __syncthreads();
    const float4* wrow = (const float4*)(fw1 + (size_t)tid * 128);
    float s = fb1[tid];
    #pragma unroll
    for (int i = 0; i < 32; ++i) {
        float4 w = wrow[i];
        s = fmaf(w.x, sF[4 * i], s);
        s = fmaf(w.y, sF[4 * i + 1], s);
        s = fmaf(w.z, sF[4 * i + 2], s);
        s = fmaf(w.w, sF[4 * i + 3], s);
    }
    sH[tid] = fmaxf(s, 0.f);
    __syncthreads();
    if (tid < 5) {
        const float* w2r = fw2 + (size_t)tid * 128;
        float s2 = fb2[tid];
        for (int i = 0; i < 128; ++i) s2 = fmaf(w2r[i], sH[i], s2);
        out[(size_t)b * 5 + tid] = s2;
    }
}

// ---------------- launch ----------------
extern "C" void kernel_launch(void* const* d_in, const int* in_sizes, int n_in,
                              void* d_out, int out_size, void* d_ws, size_t ws_size,
                              hipStream_t stream) {
    const int*   x   = (const int*)d_in[0];
    const float* w1  = (const float*)d_in[1];
    const float* b1  = (const float*)d_in[2];
    const float* w2  = (const float*)d_in[3];
    const float* b2  = (const float*)d_in[4];
    const float* w3  = (const float*)d_in[5];
    const float* b3  = (const float*)d_in[6];
    const float* fw1 = (const float*)d_in[7];
    const float* fb1 = (const float*)d_in[8];
    const float* fw2 = (const float*)d_in[9];
    const float* fb2 = (const float*)d_in[10];
    float* out = (float*)d_out;

    float* ws  = (float*)d_ws;
    float* t_c  = ws;
    float* c1_c = t_c + T_ELEMS;
    float* p1_c = c1_c + C1_ELEMS;
    float* c2_c = p1_c + P1_ELEMS;
    float* p2_c = c2_c + C2_ELEMS;
    float* c3_c = p2_c + P2_ELEMS;
    float* feat = c3_c + C3_ELEMS;
    // total: ~170.3 MB of ws_size

    for (int ch = 0; ch < NCHUNK; ++ch) {
        int b0 = ch * CHUNK;
        rasterize_k<<<CHUNK * F, 256, 0, stream>>>(x, t_c, b0);
        conv1_k<<<dim3(16, CHUNK), 256, 0, stream>>>(t_c, w1, b1, c1_c);
        pool1_k<<<(CHUNK * 32 * 31 * 31 + 255) / 256, 256, 0, stream>>>(c1_c, p1_c);
        conv2_k<<<dim3(4, CHUNK), 256, 0, stream>>>(p1_c, w2, b2, c2_c);
        pool2_k<<<(CHUNK * 64 * 15 * 15 + 255) / 256, 256, 0, stream>>>(c2_c, p2_c);
        conv3_k<<<dim3(4, CHUNK), 256, 0, stream>>>(p2_c, w3, b3, c3_c);
        pool3mean_k<<<(CHUNK * 128 + 255) / 256, 256, 0, stream>>>(c3_c, feat, b0);
    }
    fc_k<<<Bfull, 128, 0, stream>>>(feat, fw1, fb1, fw2, fb2, out);
}

// Round 2
// 1544.474 us; speedup vs baseline: 1.3181x; 1.3181x over previous
//
#include <hip/hip_runtime.h>
#include <cstddef>

typedef unsigned short ushort_t;
typedef unsigned uv4 __attribute__((ext_vector_type(4)));
typedef float f32x4 __attribute__((ext_vector_type(4)));

// ---------------- problem constants ----------------
constexpr int Bfull = 512;
constexpr int CHUNK = 128;
constexpr int NCHUNK = Bfull / CHUNK;
constexpr int F = 4, O = 10, H = 128, W = 128;

constexpr size_t T_ELEMS   = (size_t)CHUNK * F * H * W;
constexpr size_t C1_ELEMS  = (size_t)CHUNK * 32 * 64 * 64;
constexpr size_t P1P_ELEMS = (size_t)CHUNK * 35 * 35 * 32;   // padded bf16 planes
constexpr size_t P2_ELEMS  = (size_t)CHUNK * 64 * 15 * 15;
constexpr size_t C3_ELEMS  = (size_t)CHUNK * 128 * 15 * 15;
constexpr size_t FEAT_ELEMS = (size_t)Bfull * 128;
constexpr size_t W2P_ELEMS = (size_t)25 * 2 * 64 * 32;       // [kk][hl][oc][ic] ushort

__device__ __forceinline__ ushort_t f2bf_rne(float x) {
    unsigned u = __builtin_bit_cast(unsigned, x);
    unsigned r = (u + 0x7FFFu + ((u >> 16) & 1u)) >> 16;
    return (ushort_t)r;
}
__device__ __forceinline__ float bf2f(ushort_t b) {
    return __builtin_bit_cast(float, (unsigned)b << 16);
}

#define MFMA16(acc, a, b) \
    asm("v_mfma_f32_16x16x32_bf16 %0, %1, %2, %0" : "+v"(acc) : "v"(a), "v"(b))

// ---------------- rasterize (unchanged) ----------------
__global__ __launch_bounds__(256) void rasterize_k(const int* __restrict__ x,
                                                   float* __restrict__ t, int b0) {
    int bf = blockIdx.x;
    int b_l = bf / F, f = bf % F;
    int b = b0 + b_l;
    __shared__ int pts[O][2];
    __shared__ int ka[O - 1], kb[O - 1];
    if (threadIdx.x < O * 2)
        ((int*)pts)[threadIdx.x] = x[((size_t)(b * F + f) * O) * 2 + threadIdx.x];
    __syncthreads();
    if (threadIdx.x < O - 1) {
        int k = threadIdx.x;
        ka[k] = (pts[k][0] + 64) % 127;
        kb[k] = (64 - pts[k][1]) % 127;
    }
    __syncthreads();
    int dX = 64 + pts[O - 1][0];
    int dY = 64 - pts[O - 1][1];
    int loX = dX >= 64 ? 64 : dX + 1, hiX = dX >= 64 ? dX - 1 : 64;
    int loY = dY >= 64 ? 64 : dY + 1, hiY = dY >= 64 ? dY - 1 : 64;
    float* tp = t + (size_t)bf * (H * W);
    for (int i = threadIdx.x; i < H * W; i += 256) {
        int y = i >> 7, xx = i & 127;
        bool mX = (xx >= loX) && (xx <= hiX);
        bool mY = (y >= loY) && (y <= hiY);
        bool path = (mX && y == 64) || (mY && xx == dX);
        float v = path ? -1.f : 0.f;
        if (y >= 63 && y <= 65 && xx >= 63 && xx <= 65) v = 0.5f;
        if (y == 64 && xx == 64) v = 1.f;
        #pragma unroll
        for (int k = 0; k < O - 1; ++k) {
            int a = ka[k], bb = kb[k];
            if (y >= bb - 1 && y <= bb + 1 && xx >= a - 1 && xx <= a + 1) v = 0.5f;
            if (y == bb && xx == a) v = 1.f;
        }
        tp[i] = v;
    }
}

// ---------------- conv1 (unchanged fp32) ----------------
__global__ __launch_bounds__(256) void conv1_k(const float* __restrict__ t,
                                               const float* __restrict__ w1,
                                               const float* __restrict__ b1,
                                               float* __restrict__ c1) {
    __shared__ float sIn[4][37][37];
    __shared__ float sW[7][7][4][32];
    __shared__ float sB[32];
    int b_l = blockIdx.y;
    int tile = blockIdx.x;
    int oy0 = (tile >> 2) * 16, ox0 = (tile & 3) * 16;
    int iy0 = oy0 * 2 - 3, ix0 = ox0 * 2 - 3;
    int tid = threadIdx.x;
    for (int idx = tid; idx < 4 * 37 * 37; idx += 256) {
        int ic = idx / (37 * 37); int rem = idx % (37 * 37);
        int r = rem / 37, c = rem % 37;
        int iy = iy0 + r, ix = ix0 + c;
        float v = 0.f;
        if (iy >= 0 && iy < 128 && ix >= 0 && ix < 128)
            v = t[(((size_t)b_l * 4 + ic) * 128 + iy) * 128 + ix];
        sIn[ic][r][c] = v;
    }
    for (int idx = tid; idx < 6272; idx += 256) {
        int oc = idx & 31; int t2 = idx >> 5;
        int ic = t2 & 3;  int t3 = t2 >> 2;
        int kx = t3 % 7,  ky = t3 / 7;
        sW[ky][kx][ic][oc] = w1[((oc * 4 + ic) * 7 + ky) * 7 + kx];
    }
    if (tid < 32) sB[tid] = b1[tid];
    __syncthreads();
    int ty = tid >> 4, tx = tid & 15;
    float acc[32];
    #pragma unroll
    for (int oc = 0; oc < 32; ++oc) acc[oc] = sB[oc];
    for (int ic = 0; ic < 4; ++ic)
        for (int ky = 0; ky < 7; ++ky)
            #pragma unroll
            for (int kx = 0; kx < 7; ++kx) {
                float v = sIn[ic][2 * ty + ky][2 * tx + kx];
                const float* wp = sW[ky][kx][ic];
                #pragma unroll
                for (int oc = 0; oc < 32; ++oc) acc[oc] = fmaf(v, wp[oc], acc[oc]);
            }
    int oy = oy0 + ty, ox = ox0 + tx;
    float* outp = c1 + (size_t)b_l * 32 * 64 * 64 + (size_t)oy * 64 + ox;
    #pragma unroll
    for (int oc = 0; oc < 32; ++oc)
        outp[(size_t)oc * 64 * 64] = fmaxf(acc[oc], 0.f);
}

// ---------------- pool1b: 3x3 s2 pool + bf16 hi/lo split, padded [b][35][35][32] ----------------
__global__ __launch_bounds__(256) void pool1b_k(const float* __restrict__ c1,
                                                ushort_t* __restrict__ p1h,
                                                ushort_t* __restrict__ p1l) {
    int b_l = blockIdx.x;       // 0..127
    int pr  = blockIdx.y;       // 0..34
    int tid = threadIdx.x;
    int py = pr - 2;
    bool irow = (py >= 0 && py < 31);
    __shared__ float sIn[3][64][32];   // [r][x][ic^ (x&31)] swizzled
    if (irow) {
        int y0 = 2 * py;
        for (int i = tid; i < 3 * 64 * 32; i += 256) {
            int x = i & 63; int r = (i >> 6) % 3; int ic = i / 192;
            float v = c1[(((size_t)b_l * 32 + ic) * 64 + (y0 + r)) * 64 + x];
            sIn[r][x][ic ^ (x & 31)] = v;
        }
    }
    __syncthreads();
    size_t obase = ((size_t)b_l * 35 + pr) * 35 * 32;
    for (int j = tid; j < 35 * 32; j += 256) {
        int ic = j & 31, pc = j >> 5;
        int px = pc - 2;
        float m = 0.f;
        if (irow && px >= 0 && px < 31) {
            int x0 = 2 * px;
            #pragma unroll
            for (int r = 0; r < 3; ++r) {
                float a = fmaxf(fmaxf(sIn[r][x0][ic ^ (x0 & 31)],
                                      sIn[r][x0 + 1][ic ^ ((x0 + 1) & 31)]),
                                sIn[r][x0 + 2][ic ^ ((x0 + 2) & 31)]);
                m = fmaxf(m, a);
            }
        }
        ushort_t h = f2bf_rne(m);
        ushort_t l = f2bf_rne(m - bf2f(h));
        p1h[obase + j] = h;
        p1l[obase + j] = l;
    }
}

// ---------------- prep_w2: f32 -> bf16 hi/lo packed [kk][hl][oc][ic] ----------------
__global__ __launch_bounds__(256) void prep_w2_k(const float* __restrict__ w2,
                                                 ushort_t* __restrict__ w2p) {
    int idx = blockIdx.x * 256 + threadIdx.x;
    if (idx >= 25 * 64 * 32) return;
    int ic = idx & 31, oc = (idx >> 5) & 63, kk = idx >> 11;
    float w = w2[(size_t)(oc * 32 + ic) * 25 + kk];
    ushort_t h = f2bf_rne(w);
    ushort_t l = f2bf_rne(w - bf2f(h));
    w2p[(size_t)kk * 4096 + (idx & 2047)] = h;
    w2p[(size_t)kk * 4096 + 2048 + (idx & 2047)] = l;
}

// ---------------- conv2 MFMA + fused bias/relu/pool2 -> p2 f32 ----------------
// grid (128 b, 4 ytile), 256 thr = 4 waves: wm = oc half, wy = y half
__global__ __launch_bounds__(256) void conv2_mfma_k(const ushort_t* __restrict__ p1h,
                                                    const ushort_t* __restrict__ p1l,
                                                    const ushort_t* __restrict__ w2p,
                                                    const float* __restrict__ b2,
                                                    float* __restrict__ p2) {
    int b_l = blockIdx.x;
    int yt  = blockIdx.y;
    int wave = threadIdx.x >> 6;
    int lane = threadIdx.x & 63;
    int wm = wave & 1, wy = wave >> 1;
    int y0 = yt * 8;
    int oc0 = wm * 32;
    int lr = lane & 15, lq = lane >> 4;
    int ybase = y0 + wy * 4;

    f32x4 acc[4][2][2];
    #pragma unroll
    for (int y = 0; y < 4; ++y)
        #pragma unroll
        for (int m = 0; m < 2; ++m)
            #pragma unroll
            for (int n = 0; n < 2; ++n)
                acc[y][m][n] = (f32x4)0.f;

    const ushort_t* p1hb = p1h + (size_t)b_l * 35 * 1120;
    const ushort_t* p1lb = p1l + (size_t)b_l * 35 * 1120;
    int aoff = (oc0 + lr) * 32 + lq * 8;

    #pragma unroll 1
    for (int kk = 0; kk < 25; ++kk) {
        int ky = kk / 5, kx = kk % 5;
        const ushort_t* wb = w2p + (size_t)kk * 4096;
        uv4 ah0 = *(const uv4*)(wb + aoff);
        uv4 ah1 = *(const uv4*)(wb + aoff + 512);
        uv4 al0 = *(const uv4*)(wb + 2048 + aoff);
        uv4 al1 = *(const uv4*)(wb + 2048 + aoff + 512);
        #pragma unroll
        for (int y = 0; y < 4; ++y) {
            int pr = ybase + y + ky; pr = pr > 34 ? 34 : pr;
            size_t ro = (size_t)pr * 1120;
            #pragma unroll
            for (int xt = 0; xt < 2; ++xt) {
                int pc = xt * 16 + lr + kx; pc = pc > 34 ? 34 : pc;
                size_t off = ro + (size_t)pc * 32 + lq * 8;
                uv4 bh = *(const uv4*)(p1hb + off);
                uv4 bl = *(const uv4*)(p1lb + off);
                MFMA16(acc[y][0][xt], ah0, bh);
                MFMA16(acc[y][1][xt], ah1, bh);
                MFMA16(acc[y][0][xt], ah0, bl);
                MFMA16(acc[y][1][xt], ah1, bl);
                MFMA16(acc[y][0][xt], al0, bh);
                MFMA16(acc[y][1][xt], al1, bh);
            }
        }
    }
    asm volatile("s_nop 7\n\ts_nop 7");

    float bias[2][4];
    #pragma unroll
    for (int m = 0; m < 2; ++m)
        #pragma unroll
        for (int j = 0; j < 4; ++j)
            bias[m][j] = b2[oc0 + m * 16 + lq * 4 + j];

    #pragma unroll
    for (int yp = 0; yp < 2; ++yp) {
        int yy = ybase + 2 * yp;
        if (yy + 1 > 30) continue;   // wave-uniform
        int py = yy >> 1;
        #pragma unroll
        for (int m = 0; m < 2; ++m)
            #pragma unroll
            for (int xt = 0; xt < 2; ++xt)
                #pragma unroll
                for (int j = 0; j < 4; ++j) {
                    float v = fmaxf(acc[2 * yp][m][xt][j], acc[2 * yp + 1][m][xt][j]);
                    float o = __shfl_xor(v, 1, 64);
                    v = fmaxf(fmaxf(v, o) + bias[m][j], 0.f);
                    int px = xt * 8 + (lr >> 1);
                    if (!(lane & 1) && px < 15) {
                        int oc = oc0 + m * 16 + lq * 4 + j;
                        p2[(((size_t)b_l * 64 + oc) * 15 + py) * 15 + px] = v;
                    }
                }
    }
}

// ---------------- conv3 (unchanged fp32) ----------------
__global__ __launch_bounds__(256) void conv3_k(const float* __restrict__ p2,
                                               const float* __restrict__ w3,
                                               const float* __restrict__ b3,
                                               float* __restrict__ c3) {
    __shared__ float sIn[16][17][17];
    __shared__ float sW[3][3][16][32];
    int b_l = blockIdx.y;
    int oc0 = blockIdx.x * 32;
    int tid = threadIdx.x;
    int oy = tid / 15, ox = tid % 15;
    bool act = tid < 225;
    float acc[32];
    #pragma unroll
    for (int i = 0; i < 32; ++i) acc[i] = 0.f;
    for (int icc = 0; icc < 4; ++icc) {
        int ic0 = icc * 16;
        for (int idx = tid; idx < 16 * 17 * 17; idx += 256) {
            int c = idx % 17; int t1 = idx / 17;
            int r = t1 % 17;  int ic = t1 / 17;
            int iy = r - 1, ix = c - 1;
            float v = 0.f;
            if (iy >= 0 && iy < 15 && ix >= 0 && ix < 15)
                v = p2[(((size_t)b_l * 64 + ic0 + ic) * 15 + iy) * 15 + ix];
            sIn[ic][r][c] = v;
        }
        for (int idx = tid; idx < 3 * 3 * 16 * 32; idx += 256) {
            int oc = idx & 31; int t1 = idx >> 5;
            int ic = t1 & 15;  int t2 = t1 >> 4;
            int kx = t2 % 3,   ky = t2 / 3;
            sW[ky][kx][ic][oc] = w3[(((size_t)(oc0 + oc) * 64 + ic0 + ic) * 3 + ky) * 3 + kx];
        }
        __syncthreads();
        if (act) {
            for (int ic = 0; ic < 16; ++ic)
                #pragma unroll
                for (int ky = 0; ky < 3; ++ky)
                    #pragma unroll
                    for (int kx = 0; kx < 3; ++kx) {
                        float v = sIn[ic][oy + ky][ox + kx];
                        const float* wp = sW[ky][kx][ic];
                        #pragma unroll
                        for (int oc = 0; oc < 32; ++oc) acc[oc] = fmaf(v, wp[oc], acc[oc]);
                    }
        }
        __syncthreads();
    }
    if (act) {
        float* outp = c3 + ((size_t)b_l * 128 + oc0) * 225 + oy * 15 + ox;
        #pragma unroll
        for (int oc = 0; oc < 32; ++oc)
            outp[(size_t)oc * 225] = fmaxf(acc[oc] + b3[oc0 + oc], 0.f);
    }
}

// ---------------- pool3 + mean ----------------
__global__ __launch_bounds__(256) void pool3mean_k(const float* __restrict__ c3,
                                                   float* __restrict__ feat, int b0) {
    int idx = blockIdx.x * 256 + threadIdx.x;
    if (idx >= CHUNK * 128) return;
    int oc = idx & 127, b_l = idx >> 7;
    const float* base = c3 + (size_t)idx * 225;
    float s = 0.f;
    #pragma unroll
    for (int py = 0; py < 7; ++py)
        #pragma unroll
        for (int px = 0; px < 7; ++px) {
            float m = fmaxf(fmaxf(base[(2 * py) * 15 + 2 * px],     base[(2 * py) * 15 + 2 * px + 1]),
                            fmaxf(base[(2 * py + 1) * 15 + 2 * px], base[(2 * py + 1) * 15 + 2 * px + 1]));
            s += m;
        }
    feat[(size_t)(b0 + b_l) * 128 + oc] = s * (1.f / 49.f);
}

// ---------------- fc1 (relu) + fc2 ----------------
__global__ __launch_bounds__(128) void fc_k(const float* __restrict__ feat,
                                            const float* __restrict__ fw1,
                                            const float* __restrict__ fb1,
                                            const float* __restrict__ fw2,
                                            const float* __restrict__ fb2,
                                            float* __restrict__ out) {
    __shared__ float sF[128];
    __shared__ float sH[128];
    int b = blockIdx.x, tid = threadIdx.x;
    sF[tid] = feat[(size_t)b * 128 + tid];
    __syncthreads();
    const float4* wrow = (const float4*)(fw1 + (size_t)tid * 128);
    float s = fb1[tid];
    #pragma unroll
    for (int i = 0; i < 32; ++i) {
        float4 w = wrow[i];
        s = fmaf(w.x, sF[4 * i], s);
        s = fmaf(w.y, sF[4 * i + 1], s);
        s = fmaf(w.z, sF[4 * i + 2], s);
        s = fmaf(w.w, sF[4 * i + 3], s);
    }
    sH[tid] = fmaxf(s, 0.f);
    __syncthreads();
    if (tid < 5) {
        const float* w2r = fw2 + (size_t)tid * 128;
        float s2 = fb2[tid];
        for (int i = 0; i < 128; ++i) s2 = fmaf(w2r[i], sH[i], s2);
        out[(size_t)b * 5 + tid] = s2;
    }
}

// ---------------- launch ----------------
extern "C" void kernel_launch(void* const* d_in, const int* in_sizes, int n_in,
                              void* d_out, int out_size, void* d_ws, size_t ws_size,
                              hipStream_t stream) {
    const int*   x   = (const int*)d_in[0];
    const float* w1  = (const float*)d_in[1];
    const float* b1  = (const float*)d_in[2];
    const float* w2  = (const float*)d_in[3];
    const float* b2  = (const float*)d_in[4];
    const float* w3  = (const float*)d_in[5];
    const float* b3  = (const float*)d_in[6];
    const float* fw1 = (const float*)d_in[7];
    const float* fb1 = (const float*)d_in[8];
    const float* fw2 = (const float*)d_in[9];
    const float* fb2 = (const float*)d_in[10];
    float* out = (float*)d_out;

    float* ws   = (float*)d_ws;
    float* t_c  = ws;
    float* c1_c = t_c + T_ELEMS;
    ushort_t* p1h = (ushort_t*)(c1_c + C1_ELEMS);
    ushort_t* p1l = p1h + P1P_ELEMS;
    float* p2_c = (float*)(p1l + P1P_ELEMS);
    float* c3_c = p2_c + P2_ELEMS;
    float* feat = c3_c + C3_ELEMS;
    ushort_t* w2p = (ushort_t*)(feat + FEAT_ELEMS);
    // total ~143 MB (< the 170 MB layout that round-1 ran with)

    prep_w2_k<<<(25 * 64 * 32 + 255) / 256, 256, 0, stream>>>(w2, w2p);

    for (int ch = 0; ch < NCHUNK; ++ch) {
        int b0 = ch * CHUNK;
        rasterize_k<<<CHUNK * F, 256, 0, stream>>>(x, t_c, b0);
        conv1_k<<<dim3(16, CHUNK), 256, 0, stream>>>(t_c, w1, b1, c1_c);
        pool1b_k<<<dim3(CHUNK, 35), 256, 0, stream>>>(c1_c, p1h, p1l);
        conv2_mfma_k<<<dim3(CHUNK, 4), 256, 0, stream>>>(p1h, p1l, w2p, b2, p2_c);
        conv3_k<<<dim3(4, CHUNK), 256, 0, stream>>>(p2_c, w3, b3, c3_c);
        pool3mean_k<<<(CHUNK * 128 + 255) / 256, 256, 0, stream>>>(c3_c, feat, b0);
    }
    fc_k<<<Bfull, 128, 0, stream>>>(feat, fw1, fb1, fw2, fb2, out);
}

// Round 3
// 1332.480 us; speedup vs baseline: 1.5278x; 1.1591x over previous
//
#include <hip/hip_runtime.h>
#include <cstddef>

typedef unsigned short ushort_t;
typedef unsigned uv4 __attribute__((ext_vector_type(4)));
typedef unsigned uv2 __attribute__((ext_vector_type(2)));
typedef float f32x4 __attribute__((ext_vector_type(4)));

// ---------------- problem constants ----------------
constexpr int Bfull = 512;
constexpr int CHUNK = 128;
constexpr int NCHUNK = Bfull / CHUNK;
constexpr int F = 4, O = 10;

constexpr size_t TB_ELEMS  = (size_t)CHUNK * 136 * 136 * 4;   // bf16, padded raster
constexpr size_t C1_ELEMS  = (size_t)CHUNK * 32 * 64 * 64;    // f32
constexpr size_t P1P_ELEMS = (size_t)CHUNK * 35 * 35 * 32;    // bf16 planes (h,l)
constexpr size_t P2P_ELEMS = (size_t)CHUNK * 17 * 18 * 64;    // bf16 planes (h,l), padded
constexpr size_t C3_ELEMS  = (size_t)CHUNK * 128 * 15 * 15;   // f32
constexpr size_t FEAT_ELEMS = (size_t)Bfull * 128;            // f32
constexpr size_t W1P_ELEMS = (size_t)7 * 4 * 16 * 32;         // 28672 ushort
constexpr size_t W2P_ELEMS = (size_t)25 * 2 * 64 * 32;        // 102400 ushort
constexpr size_t W3P_ELEMS = (size_t)9 * 2 * 2 * 128 * 32;    // 147456 ushort

__device__ __forceinline__ ushort_t f2bf_rne(float x) {
    unsigned u = __builtin_bit_cast(unsigned, x);
    unsigned r = (u + 0x7FFFu + ((u >> 16) & 1u)) >> 16;
    return (ushort_t)r;
}
__device__ __forceinline__ float bf2f(ushort_t b) {
    return __builtin_bit_cast(float, (unsigned)b << 16);
}

#define MFMA16(acc, a, b) \
    asm("v_mfma_f32_16x16x32_bf16 %0, %1, %2, %0" : "+v"(acc) : "v"(a), "v"(b))

// ---------------- rasterize -> padded bf16 [b][136r][136c][4ic] ----------------
__global__ __launch_bounds__(256) void rasterize_bf_k(const int* __restrict__ x,
                                                      ushort_t* __restrict__ tb, int b0) {
    int b_l = blockIdx.x;
    int b = b0 + b_l;
    __shared__ int pts[F][O][2];
    __shared__ int prm[F][24];   // dX,dY,loX,hiX,loY,hiY, ka[9]@6, kb[9]@15
    int tid = threadIdx.x;
    if (tid < F * O * 2)
        ((int*)pts)[tid] = x[(size_t)b * F * O * 2 + tid];
    __syncthreads();
    if (tid < F) {
        int f = tid;
        int dX = 64 + pts[f][O - 1][0];
        int dY = 64 - pts[f][O - 1][1];
        prm[f][0] = dX; prm[f][1] = dY;
        prm[f][2] = dX >= 64 ? 64 : dX + 1; prm[f][3] = dX >= 64 ? dX - 1 : 64;
        prm[f][4] = dY >= 64 ? 64 : dY + 1; prm[f][5] = dY >= 64 ? dY - 1 : 64;
        for (int k = 0; k < O - 1; ++k) {
            prm[f][6 + k]  = (pts[f][k][0] + 64) % 127;
            prm[f][15 + k] = (64 - pts[f][k][1]) % 127;
        }
    }
    __syncthreads();
    ushort_t* outp = tb + (size_t)b_l * 136 * 136 * 4;
    for (int i = tid; i < 136 * 136; i += 256) {
        int r = i / 136, c = i % 136;
        int y = r - 3, xx = c - 3;
        unsigned pack0 = 0, pack1 = 0;
        if (y >= 0 && y < 128 && xx >= 0 && xx < 128) {
            #pragma unroll
            for (int f = 0; f < 4; ++f) {
                int dX = prm[f][0];
                bool mX = (xx >= prm[f][2]) && (xx <= prm[f][3]);
                bool mY = (y >= prm[f][4]) && (y <= prm[f][5]);
                bool path = (mX && y == 64) || (mY && xx == dX);
                float v = path ? -1.f : 0.f;
                if (y >= 63 && y <= 65 && xx >= 63 && xx <= 65) v = 0.5f;
                if (y == 64 && xx == 64) v = 1.f;
                #pragma unroll
                for (int k = 0; k < O - 1; ++k) {
                    int a = prm[f][6 + k], bb = prm[f][15 + k];
                    if (y >= bb - 1 && y <= bb + 1 && xx >= a - 1 && xx <= a + 1) v = 0.5f;
                    if (y == bb && xx == a) v = 1.f;
                }
                unsigned bf = (unsigned)f2bf_rne(v);
                if (f & 1) { if (f >> 1) pack1 |= bf << 16; else pack0 |= bf << 16; }
                else       { if (f >> 1) pack1 |= bf;       else pack0 |= bf; }
            }
        }
        uv2 pk; pk.x = pack0; pk.y = pack1;
        *(uv2*)(outp + (size_t)i * 4) = pk;
    }
}

// ---------------- prep_w1: [ky][m*2+hl][oc16][k32], k = kx*4+ic (kx 0..7, kx=7 -> 0) ----------------
__global__ __launch_bounds__(256) void prep_w1_k(const float* __restrict__ w1,
                                                 ushort_t* __restrict__ w1p) {
    int idx = blockIdx.x * 256 + threadIdx.x;
    if (idx >= (int)W1P_ELEMS) return;
    int k = idx & 31, lr = (idx >> 5) & 15, slot = (idx >> 9) & 3, ky = idx >> 11;
    int hl = slot & 1, m = slot >> 1;
    int kx = k >> 2, ic = k & 3;
    int oc = m * 16 + lr;
    float w = (kx < 7) ? w1[((oc * 4 + ic) * 7 + ky) * 7 + kx] : 0.f;
    ushort_t h = f2bf_rne(w);
    w1p[idx] = hl ? f2bf_rne(w - bf2f(h)) : h;
}

// ---------------- conv1 MFMA: 2-pass (input exact bf16), +bias+relu -> c1 f32 ----------------
// grid (b, 4 oyt), 4 waves; wave covers oy = oyt*16 + wave*4 .. +3, all 32 oc, 64 ox
__global__ __launch_bounds__(256) void conv1_mfma_k(const ushort_t* __restrict__ tb,
                                                    const ushort_t* __restrict__ w1p,
                                                    const float* __restrict__ b1,
                                                    float* __restrict__ c1) {
    int b_l = blockIdx.x;
    int oyt = blockIdx.y;
    int wave = threadIdx.x >> 6, lane = threadIdx.x & 63;
    int lr = lane & 15, lq = lane >> 4;
    const ushort_t* tbb = tb + (size_t)b_l * 136 * 136 * 4;
    int aoff = lr * 32 + lq * 8;
    float bias[2][4];
    #pragma unroll
    for (int m = 0; m < 2; ++m)
        #pragma unroll
        for (int j = 0; j < 4; ++j)
            bias[m][j] = b1[m * 16 + lq * 4 + j];
    int oybase = oyt * 16 + wave * 4;
    #pragma unroll 1
    for (int yy = 0; yy < 4; ++yy) {
        int oy = oybase + yy;
        f32x4 acc[2][4];
        #pragma unroll
        for (int m = 0; m < 2; ++m)
            #pragma unroll
            for (int xt = 0; xt < 4; ++xt)
                acc[m][xt] = (f32x4)0.f;
        #pragma unroll
        for (int ky = 0; ky < 7; ++ky) {
            const ushort_t* wb = w1p + (size_t)ky * 2048;
            uv4 ah0 = *(const uv4*)(wb + aoff);
            uv4 al0 = *(const uv4*)(wb + 512 + aoff);
            uv4 ah1 = *(const uv4*)(wb + 1024 + aoff);
            uv4 al1 = *(const uv4*)(wb + 1536 + aoff);
            const ushort_t* rb = tbb + (size_t)(2 * oy + ky) * (136 * 4);
            #pragma unroll
            for (int xt = 0; xt < 4; ++xt) {
                uv4 bv = *(const uv4*)(rb + (size_t)(2 * (xt * 16 + lr) + 2 * lq) * 4);
                MFMA16(acc[0][xt], ah0, bv);
                MFMA16(acc[1][xt], ah1, bv);
                MFMA16(acc[0][xt], al0, bv);
                MFMA16(acc[1][xt], al1, bv);
            }
        }
        asm volatile("s_nop 7\n\ts_nop 7");
        #pragma unroll
        for (int m = 0; m < 2; ++m)
            #pragma unroll
            for (int xt = 0; xt < 4; ++xt)
                #pragma unroll
                for (int j = 0; j < 4; ++j) {
                    int oc = m * 16 + lq * 4 + j;
                    float v = fmaxf(acc[m][xt][j] + bias[m][j], 0.f);
                    c1[(((size_t)b_l * 32 + oc) * 64 + oy) * 64 + xt * 16 + lr] = v;
                }
    }
}

// ---------------- pool1b: 3x3 s2 pool + bf16 hi/lo split, padded [b][35][35][32] ----------------
__global__ __launch_bounds__(256) void pool1b_k(const float* __restrict__ c1,
                                                ushort_t* __restrict__ p1h,
                                                ushort_t* __restrict__ p1l) {
    int b_l = blockIdx.x;
    int pr  = blockIdx.y;       // 0..34
    int tid = threadIdx.x;
    int py = pr - 2;
    bool irow = (py >= 0 && py < 31);
    __shared__ float sIn[3][64][32];
    if (irow) {
        int y0 = 2 * py;
        for (int i = tid; i < 3 * 64 * 32; i += 256) {
            int xx = i & 63; int r = (i >> 6) % 3; int ic = i / 192;
            float v = c1[(((size_t)b_l * 32 + ic) * 64 + (y0 + r)) * 64 + xx];
            sIn[r][xx][ic ^ (xx & 31)] = v;
        }
    }
    __syncthreads();
    size_t obase = ((size_t)b_l * 35 + pr) * 35 * 32;
    for (int j = tid; j < 35 * 32; j += 256) {
        int ic = j & 31, pc = j >> 5;
        int px = pc - 2;
        float m = 0.f;
        if (irow && px >= 0 && px < 31) {
            int x0 = 2 * px;
            #pragma unroll
            for (int r = 0; r < 3; ++r) {
                float a = fmaxf(fmaxf(sIn[r][x0][ic ^ (x0 & 31)],
                                      sIn[r][x0 + 1][ic ^ ((x0 + 1) & 31)]),
                                sIn[r][x0 + 2][ic ^ ((x0 + 2) & 31)]);
                m = fmaxf(m, a);
            }
        }
        ushort_t h = f2bf_rne(m);
        p1h[obase + j] = h;
        p1l[obase + j] = f2bf_rne(m - bf2f(h));
    }
}

// ---------------- prep_w2 (unchanged) ----------------
__global__ __launch_bounds__(256) void prep_w2_k(const float* __restrict__ w2,
                                                 ushort_t* __restrict__ w2p) {
    int idx = blockIdx.x * 256 + threadIdx.x;
    if (idx >= 25 * 64 * 32) return;
    int ic = idx & 31, oc = (idx >> 5) & 63, kk = idx >> 11;
    float w = w2[(size_t)(oc * 32 + ic) * 25 + kk];
    ushort_t h = f2bf_rne(w);
    w2p[(size_t)kk * 4096 + (idx & 2047)] = h;
    w2p[(size_t)kk * 4096 + 2048 + (idx & 2047)] = f2bf_rne(w - bf2f(h));
}

// ---------------- zero p2 padded buffers ----------------
__global__ __launch_bounds__(256) void zero_k(unsigned* __restrict__ p, int n) {
    int i = blockIdx.x * 256 + threadIdx.x;
    if (i < n) p[i] = 0u;
}

// ---------------- conv2 MFMA + fused bias/relu/pool2 -> p2 bf16 hi/lo padded ----------------
__global__ __launch_bounds__(256) void conv2_mfma_k(const ushort_t* __restrict__ p1h,
                                                    const ushort_t* __restrict__ p1l,
                                                    const ushort_t* __restrict__ w2p,
                                                    const float* __restrict__ b2,
                                                    ushort_t* __restrict__ p2h,
                                                    ushort_t* __restrict__ p2l) {
    int b_l = blockIdx.x;
    int yt  = blockIdx.y;
    int wave = threadIdx.x >> 6;
    int lane = threadIdx.x & 63;
    int wm = wave & 1, wy = wave >> 1;
    int y0 = yt * 8;
    int oc0 = wm * 32;
    int lr = lane & 15, lq = lane >> 4;
    int ybase = y0 + wy * 4;

    f32x4 acc[4][2][2];
    #pragma unroll
    for (int y = 0; y < 4; ++y)
        #pragma unroll
        for (int m = 0; m < 2; ++m)
            #pragma unroll
            for (int n = 0; n < 2; ++n)
                acc[y][m][n] = (f32x4)0.f;

    const ushort_t* p1hb = p1h + (size_t)b_l * 35 * 1120;
    const ushort_t* p1lb = p1l + (size_t)b_l * 35 * 1120;
    int aoff = (oc0 + lr) * 32 + lq * 8;

    #pragma unroll 1
    for (int kk = 0; kk < 25; ++kk) {
        int ky = kk / 5, kx = kk % 5;
        const ushort_t* wb = w2p + (size_t)kk * 4096;
        uv4 ah0 = *(const uv4*)(wb + aoff);
        uv4 ah1 = *(const uv4*)(wb + aoff + 512);
        uv4 al0 = *(const uv4*)(wb + 2048 + aoff);
        uv4 al1 = *(const uv4*)(wb + 2048 + aoff + 512);
        #pragma unroll
        for (int y = 0; y < 4; ++y) {
            int pr = ybase + y + ky; pr = pr > 34 ? 34 : pr;
            size_t ro = (size_t)pr * 1120;
            #pragma unroll
            for (int xt = 0; xt < 2; ++xt) {
                int pc = xt * 16 + lr + kx; pc = pc > 34 ? 34 : pc;
                size_t off = ro + (size_t)pc * 32 + lq * 8;
                uv4 bh = *(const uv4*)(p1hb + off);
                uv4 bl = *(const uv4*)(p1lb + off);
                MFMA16(acc[y][0][xt], ah0, bh);
                MFMA16(acc[y][1][xt], ah1, bh);
                MFMA16(acc[y][0][xt], ah0, bl);
                MFMA16(acc[y][1][xt], ah1, bl);
                MFMA16(acc[y][0][xt], al0, bh);
                MFMA16(acc[y][1][xt], al1, bh);
            }
        }
    }
    asm volatile("s_nop 7\n\ts_nop 7");

    float bias[2][4];
    #pragma unroll
    for (int m = 0; m < 2; ++m)
        #pragma unroll
        for (int j = 0; j < 4; ++j)
            bias[m][j] = b2[oc0 + m * 16 + lq * 4 + j];

    #pragma unroll
    for (int yp = 0; yp < 2; ++yp) {
        int yy = ybase + 2 * yp;
        if (yy + 1 > 30) continue;   // wave-uniform
        int py = yy >> 1;
        #pragma unroll
        for (int m = 0; m < 2; ++m)
            #pragma unroll
            for (int xt = 0; xt < 2; ++xt)
                #pragma unroll
                for (int j = 0; j < 4; ++j) {
                    float v = fmaxf(acc[2 * yp][m][xt][j], acc[2 * yp + 1][m][xt][j]);
                    float o = __shfl_xor(v, 1, 64);
                    v = fmaxf(fmaxf(v, o) + bias[m][j], 0.f);
                    int px = xt * 8 + (lr >> 1);
                    if (!(lane & 1) && px < 15) {
                        int oc = oc0 + m * 16 + lq * 4 + j;
                        size_t oo = (((size_t)b_l * 17 + py + 1) * 18 + px + 1) * 64 + oc;
                        ushort_t h = f2bf_rne(v);
                        p2h[oo] = h;
                        p2l[oo] = f2bf_rne(v - bf2f(h));
                    }
                }
    }
}

// ---------------- prep_w3: [ky*3+kx][ks][hl][oc128][kk32] ----------------
__global__ __launch_bounds__(256) void prep_w3_k(const float* __restrict__ w3,
                                                 ushort_t* __restrict__ w3p) {
    int idx = blockIdx.x * 256 + threadIdx.x;
    if (idx >= (int)W3P_ELEMS) return;
    int kk = idx & 31, oc = (idx >> 5) & 127, hl = (idx >> 12) & 1, ks = (idx >> 13) & 1, kxy = idx >> 14;
    int ky = kxy / 3, kx = kxy % 3;
    int ic = ks * 32 + kk;
    float w = w3[((size_t)(oc * 64 + ic) * 3 + ky) * 3 + kx];
    ushort_t h = f2bf_rne(w);
    w3p[idx] = hl ? f2bf_rne(w - bf2f(h)) : h;
}

// ---------------- conv3 MFMA: 3-pass hi/lo, +bias+relu -> c3 f32 ----------------
// grid (b, 3 oy-groups of 5), 4 waves; wave = 32 oc
__global__ __launch_bounds__(256) void conv3_mfma_k(const ushort_t* __restrict__ p2h,
                                                    const ushort_t* __restrict__ p2l,
                                                    const ushort_t* __restrict__ w3p,
                                                    const float* __restrict__ b3,
                                                    float* __restrict__ c3) {
    int b_l = blockIdx.x;
    int oy0 = blockIdx.y * 5;
    int wave = threadIdx.x >> 6, lane = threadIdx.x & 63;
    int lr = lane & 15, lq = lane >> 4;
    int oc0 = wave * 32;
    const ushort_t* ph = p2h + (size_t)b_l * 17 * 18 * 64;
    const ushort_t* pl = p2l + (size_t)b_l * 17 * 18 * 64;
    f32x4 acc[5][2];
    #pragma unroll
    for (int y = 0; y < 5; ++y) { acc[y][0] = (f32x4)0.f; acc[y][1] = (f32x4)0.f; }

    #pragma unroll 1
    for (int ky = 0; ky < 3; ++ky)
        #pragma unroll 1
        for (int kx = 0; kx < 3; ++kx)
            #pragma unroll
            for (int ks = 0; ks < 2; ++ks) {
                const ushort_t* wb = w3p + (size_t)(((ky * 3 + kx) * 2 + ks) * 2) * 4096;
                uv4 ah0 = *(const uv4*)(wb + (oc0 + lr) * 32 + lq * 8);
                uv4 ah1 = *(const uv4*)(wb + (oc0 + 16 + lr) * 32 + lq * 8);
                uv4 al0 = *(const uv4*)(wb + 4096 + (oc0 + lr) * 32 + lq * 8);
                uv4 al1 = *(const uv4*)(wb + 4096 + (oc0 + 16 + lr) * 32 + lq * 8);
                #pragma unroll
                for (int yy = 0; yy < 5; ++yy) {
                    size_t off = ((size_t)(oy0 + yy + ky) * 18 + lr + kx) * 64 + ks * 32 + lq * 8;
                    uv4 bh = *(const uv4*)(ph + off);
                    uv4 bl = *(const uv4*)(pl + off);
                    MFMA16(acc[yy][0], ah0, bh);
                    MFMA16(acc[yy][1], ah1, bh);
                    MFMA16(acc[yy][0], ah0, bl);
                    MFMA16(acc[yy][1], ah1, bl);
                    MFMA16(acc[yy][0], al0, bh);
                    MFMA16(acc[yy][1], al1, bh);
                }
            }
    asm volatile("s_nop 7\n\ts_nop 7");
    if (lr < 15) {
        #pragma unroll
        for (int yy = 0; yy < 5; ++yy)
            #pragma unroll
            for (int m = 0; m < 2; ++m)
                #pragma unroll
                for (int j = 0; j < 4; ++j) {
                    int oc = oc0 + m * 16 + lq * 4 + j;
                    float v = fmaxf(acc[yy][m][j] + b3[oc], 0.f);
                    c3[((size_t)b_l * 128 + oc) * 225 + (oy0 + yy) * 15 + lr] = v;
                }
    }
}

// ---------------- pool3 + mean ----------------
__global__ __launch_bounds__(256) void pool3mean_k(const float* __restrict__ c3,
                                                   float* __restrict__ feat, int b0) {
    int idx = blockIdx.x * 256 + threadIdx.x;
    if (idx >= CHUNK * 128) return;
    int oc = idx & 127, b_l = idx >> 7;
    const float* base = c3 + (size_t)idx * 225;
    float s = 0.f;
    #pragma unroll
    for (int py = 0; py < 7; ++py)
        #pragma unroll
        for (int px = 0; px < 7; ++px) {
            float m = fmaxf(fmaxf(base[(2 * py) * 15 + 2 * px],     base[(2 * py) * 15 + 2 * px + 1]),
                            fmaxf(base[(2 * py + 1) * 15 + 2 * px], base[(2 * py + 1) * 15 + 2 * px + 1]));
            s += m;
        }
    feat[(size_t)(b0 + b_l) * 128 + oc] = s * (1.f / 49.f);
}

// ---------------- fc1 (relu) + fc2 ----------------
__global__ __launch_bounds__(128) void fc_k(const float* __restrict__ feat,
                                            const float* __restrict__ fw1,
                                            const float* __restrict__ fb1,
                                            const float* __restrict__ fw2,
                                            const float* __restrict__ fb2,
                                            float* __restrict__ out) {
    __shared__ float sF[128];
    __shared__ float sH[128];
    int b = blockIdx.x, tid = threadIdx.x;
    sF[tid] = feat[(size_t)b * 128 + tid];
    __syncthreads();
    const float4* wrow = (const float4*)(fw1 + (size_t)tid * 128);
    float s = fb1[tid];
    #pragma unroll
    for (int i = 0; i < 32; ++i) {
        float4 w = wrow[i];
        s = fmaf(w.x, sF[4 * i], s);
        s = fmaf(w.y, sF[4 * i + 1], s);
        s = fmaf(w.z, sF[4 * i + 2], s);
        s = fmaf(w.w, sF[4 * i + 3], s);
    }
    sH[tid] = fmaxf(s, 0.f);
    __syncthreads();
    if (tid < 5) {
        const float* w2r = fw2 + (size_t)tid * 128;
        float s2 = fb2[tid];
        for (int i = 0; i < 128; ++i) s2 = fmaf(w2r[i], sH[i], s2);
        out[(size_t)b * 5 + tid] = s2;
    }
}

// ---------------- launch ----------------
extern "C" void kernel_launch(void* const* d_in, const int* in_sizes, int n_in,
                              void* d_out, int out_size, void* d_ws, size_t ws_size,
                              hipStream_t stream) {
    const int*   x   = (const int*)d_in[0];
    const float* w1  = (const float*)d_in[1];
    const float* b1  = (const float*)d_in[2];
    const float* w2  = (const float*)d_in[3];
    const float* b2  = (const float*)d_in[4];
    const float* w3  = (const float*)d_in[5];
    const float* b3  = (const float*)d_in[6];
    const float* fw1 = (const float*)d_in[7];
    const float* fb1 = (const float*)d_in[8];
    const float* fw2 = (const float*)d_in[9];
    const float* fb2 = (const float*)d_in[10];
    float* out = (float*)d_out;

    float* ws   = (float*)d_ws;
    float* c1_c = ws;                              // 16,777,216 f32
    float* c3_c = c1_c + C1_ELEMS;                 //  3,686,400 f32
    float* feat = c3_c + C3_ELEMS;                 //     65,536 f32
    ushort_t* tb  = (ushort_t*)(feat + FEAT_ELEMS);
    ushort_t* p1h = tb + TB_ELEMS;
    ushort_t* p1l = p1h + P1P_ELEMS;
    ushort_t* p2h = p1l + P1P_ELEMS;
    ushort_t* p2l = p2h + P2P_ELEMS;               // contiguous after p2h (zeroed together)
    ushort_t* w1p = p2l + P2P_ELEMS;
    ushort_t* w2p = w1p + W1P_ELEMS;
    ushort_t* w3p = w2p + W2P_ELEMS;
    // total ~132 MB

    prep_w1_k<<<((int)W1P_ELEMS + 255) / 256, 256, 0, stream>>>(w1, w1p);
    prep_w2_k<<<(25 * 64 * 32 + 255) / 256, 256, 0, stream>>>(w2, w2p);
    prep_w3_k<<<((int)W3P_ELEMS + 255) / 256, 256, 0, stream>>>(w3, w3p);

    int p2_uints = (int)(2 * P2P_ELEMS / 2);
    for (int ch = 0; ch < NCHUNK; ++ch) {
        int b0 = ch * CHUNK;
        rasterize_bf_k<<<CHUNK, 256, 0, stream>>>(x, tb, b0);
        conv1_mfma_k<<<dim3(CHUNK, 4), 256, 0, stream>>>(tb, w1p, b1, c1_c);
        pool1b_k<<<dim3(CHUNK, 35), 256, 0, stream>>>(c1_c, p1h, p1l);
        zero_k<<<(p2_uints + 255) / 256, 256, 0, stream>>>((unsigned*)p2h, p2_uints);
        conv2_mfma_k<<<dim3(CHUNK, 4), 256, 0, stream>>>(p1h, p1l, w2p, b2, p2h, p2l);
        conv3_mfma_k<<<dim3(CHUNK, 3), 256, 0, stream>>>(p2h, p2l, w3p, b3, c3_c);
        pool3mean_k<<<(CHUNK * 128 + 255) / 256, 256, 0, stream>>>(c3_c, feat, b0);
    }
    fc_k<<<Bfull, 128, 0, stream>>>(feat, fw1, fb1, fw2, fb2, out);
}

// Round 5
// 870.110 us; speedup vs baseline: 2.3396x; 1.5314x over previous
//
#include <hip/hip_runtime.h>
#include <cstddef>

typedef unsigned short ushort_t;
typedef unsigned uv4 __attribute__((ext_vector_type(4)));
typedef unsigned uv2 __attribute__((ext_vector_type(2)));
typedef float f32x4 __attribute__((ext_vector_type(4)));

// ---------------- problem constants ----------------
constexpr int Bfull = 512;
constexpr int CHUNK = 128;
constexpr int NCHUNK = Bfull / CHUNK;
constexpr int F = 4, O = 10;

constexpr size_t TB_ELEMS  = (size_t)CHUNK * 136 * 136 * 4;   // bf16, padded raster
constexpr size_t C1_ELEMS  = (size_t)CHUNK * 32 * 64 * 64;    // f32
constexpr size_t P1P_ELEMS = (size_t)CHUNK * 35 * 35 * 32;    // bf16 planes (h,l)
constexpr size_t P2P_ELEMS = (size_t)CHUNK * 17 * 18 * 64;    // bf16 planes (h,l), padded
constexpr size_t C3_ELEMS  = (size_t)CHUNK * 128 * 15 * 15;   // f32
constexpr size_t FEAT_ELEMS = (size_t)Bfull * 128;            // f32
constexpr size_t W1P_ELEMS = (size_t)7 * 4 * 16 * 32;         // 28672 ushort
constexpr size_t W2P_ELEMS = (size_t)25 * 2 * 64 * 32;        // 102400 ushort
constexpr size_t W3P_ELEMS = (size_t)9 * 2 * 2 * 128 * 32;    // 147456 ushort

__device__ __forceinline__ ushort_t f2bf_rne(float x) {
    unsigned u = __builtin_bit_cast(unsigned, x);
    unsigned r = (u + 0x7FFFu + ((u >> 16) & 1u)) >> 16;
    return (ushort_t)r;
}
__device__ __forceinline__ float bf2f(ushort_t b) {
    return __builtin_bit_cast(float, (unsigned)b << 16);
}

#define MFMA16(acc, a, b) \
    asm("v_mfma_f32_16x16x32_bf16 %0, %1, %2, %0" : "+v"(acc) : "v"(a), "v"(b))

// ---------------- rasterize -> padded bf16 [b][136r][136c][4ic] ----------------
// grid (CHUNK, 8): block owns 17 padded rows. Phase 1: background+path+center
// per-pixel. Phase 2: 9 sequential 3x3 stamps per feature (1 thread/feature),
// filtered to owned rows (stamps span padded rows [36,98], always interior).
__global__ __launch_bounds__(256) void rasterize_bf_k(const int* __restrict__ x,
                                                      ushort_t* __restrict__ tb, int b0) {
    int b_l = blockIdx.x;
    int rg  = blockIdx.y;             // row-group 0..7
    int b = b0 + b_l;
    __shared__ int pts[F][O][2];
    __shared__ int prm[F][24];   // dX,_,loX,hiX,loY,hiY, ka[9]@6, kb[9]@15
    int tid = threadIdx.x;
    if (tid < F * O * 2)
        ((int*)pts)[tid] = x[(size_t)b * F * O * 2 + tid];
    __syncthreads();
    if (tid < F) {
        int f = tid;
        int dX = 64 + pts[f][O - 1][0];
        int dY = 64 - pts[f][O - 1][1];
        prm[f][0] = dX; prm[f][1] = dY;
        prm[f][2] = dX >= 64 ? 64 : dX + 1; prm[f][3] = dX >= 64 ? dX - 1 : 64;
        prm[f][4] = dY >= 64 ? 64 : dY + 1; prm[f][5] = dY >= 64 ? dY - 1 : 64;
        for (int k = 0; k < O - 1; ++k) {
            prm[f][6 + k]  = (pts[f][k][0] + 64) % 127;
            prm[f][15 + k] = (64 - pts[f][k][1]) % 127;
        }
    }
    __syncthreads();
    ushort_t* outp = tb + (size_t)b_l * 136 * 136 * 4;
    int r0 = rg * 17;
    // phase 1: background + path + center block
    for (int i = tid; i < 17 * 136; i += 256) {
        int r = r0 + i / 136, c = i % 136;
        int y = r - 3, xx = c - 3;
        unsigned pack0 = 0, pack1 = 0;
        if (y >= 0 && y < 128 && xx >= 0 && xx < 128) {
            bool ctr9 = (y >= 63 && y <= 65 && xx >= 63 && xx <= 65);
            bool ctr1 = (y == 64 && xx == 64);
            #pragma unroll
            for (int f = 0; f < 4; ++f) {
                unsigned bf;
                if (ctr1) bf = 0x3F80u;
                else if (ctr9) bf = 0x3F00u;
                else {
                    int dX = prm[f][0];
                    bool mX = (xx >= prm[f][2]) && (xx <= prm[f][3]);
                    bool mY = (y >= prm[f][4]) && (y <= prm[f][5]);
                    bf = ((mX && y == 64) || (mY && xx == dX)) ? 0xBF80u : 0u;
                }
                if (f & 1) { if (f >> 1) pack1 |= bf << 16; else pack0 |= bf << 16; }
                else       { if (f >> 1) pack1 |= bf;       else pack0 |= bf; }
            }
        }
        uv2 pk; pk.x = pack0; pk.y = pack1;
        *(uv2*)(outp + ((size_t)r * 136 + c) * 4) = pk;
    }
    __syncthreads();
    // phase 2: sequential stamps (order k=0..8 preserved per feature)
    if (tid < 4) {
        int f = tid;
        int r1 = r0 + 17;
        for (int k = 0; k < O - 1; ++k) {
            int a = prm[f][6 + k] + 3, bb = prm[f][15 + k] + 3;
            #pragma unroll
            for (int dy = -1; dy <= 1; ++dy) {
                int rr = bb + dy;
                if (rr >= r0 && rr < r1) {
                    ushort_t* rowp = outp + ((size_t)rr * 136 + a - 1) * 4 + f;
                    rowp[0] = 0x3F00u; rowp[4] = 0x3F00u; rowp[8] = 0x3F00u;
                }
            }
            if (bb >= r0 && bb < r1) outp[((size_t)bb * 136 + a) * 4 + f] = 0x3F80u;
        }
    }
}

// ---------------- prep_w1: [ky][m*2+hl][oc16][k32], k = kx*4+ic (kx 0..7, kx=7 -> 0) ----------------
__global__ __launch_bounds__(256) void prep_w1_k(const float* __restrict__ w1,
                                                 ushort_t* __restrict__ w1p) {
    int idx = blockIdx.x * 256 + threadIdx.x;
    if (idx >= (int)W1P_ELEMS) return;
    int k = idx & 31, lr = (idx >> 5) & 15, slot = (idx >> 9) & 3, ky = idx >> 11;
    int hl = slot & 1, m = slot >> 1;
    int kx = k >> 2, ic = k & 3;
    int oc = m * 16 + lr;
    float w = (kx < 7) ? w1[((oc * 4 + ic) * 7 + ky) * 7 + kx] : 0.f;
    ushort_t h = f2bf_rne(w);
    w1p[idx] = hl ? f2bf_rne(w - bf2f(h)) : h;
}

// ---------------- conv1 MFMA: 2-pass (input exact bf16), +bias+relu -> c1 f32 ----------------
__global__ __launch_bounds__(256) void conv1_mfma_k(const ushort_t* __restrict__ tb,
                                                    const ushort_t* __restrict__ w1p,
                                                    const float* __restrict__ b1,
                                                    float* __restrict__ c1) {
    int b_l = blockIdx.x;
    int oyt = blockIdx.y;
    int wave = threadIdx.x >> 6, lane = threadIdx.x & 63;
    int lr = lane & 15, lq = lane >> 4;
    const ushort_t* tbb = tb + (size_t)b_l * 136 * 136 * 4;
    int aoff = lr * 32 + lq * 8;
    float bias[2][4];
    #pragma unroll
    for (int m = 0; m < 2; ++m)
        #pragma unroll
        for (int j = 0; j < 4; ++j)
            bias[m][j] = b1[m * 16 + lq * 4 + j];
    int oybase = oyt * 16 + wave * 4;
    #pragma unroll 1
    for (int yy = 0; yy < 4; ++yy) {
        int oy = oybase + yy;
        f32x4 acc[2][4];
        #pragma unroll
        for (int m = 0; m < 2; ++m)
            #pragma unroll
            for (int xt = 0; xt < 4; ++xt)
                acc[m][xt] = (f32x4)0.f;
        #pragma unroll
        for (int ky = 0; ky < 7; ++ky) {
            const ushort_t* wb = w1p + (size_t)ky * 2048;
            uv4 ah0 = *(const uv4*)(wb + aoff);
            uv4 al0 = *(const uv4*)(wb + 512 + aoff);
            uv4 ah1 = *(const uv4*)(wb + 1024 + aoff);
            uv4 al1 = *(const uv4*)(wb + 1536 + aoff);
            const ushort_t* rb = tbb + (size_t)(2 * oy + ky) * (136 * 4);
            #pragma unroll
            for (int xt = 0; xt < 4; ++xt) {
                uv4 bv = *(const uv4*)(rb + (size_t)(2 * (xt * 16 + lr) + 2 * lq) * 4);
                MFMA16(acc[0][xt], ah0, bv);
                MFMA16(acc[1][xt], ah1, bv);
                MFMA16(acc[0][xt], al0, bv);
                MFMA16(acc[1][xt], al1, bv);
            }
        }
        asm volatile("s_nop 7\n\ts_nop 7");
        #pragma unroll
        for (int m = 0; m < 2; ++m)
            #pragma unroll
            for (int xt = 0; xt < 4; ++xt)
                #pragma unroll
                for (int j = 0; j < 4; ++j) {
                    int oc = m * 16 + lq * 4 + j;
                    float v = fmaxf(acc[m][xt][j] + bias[m][j], 0.f);
                    c1[(((size_t)b_l * 32 + oc) * 64 + oy) * 64 + xt * 16 + lr] = v;
                }
    }
}

// ---------------- pool1b: 3x3 s2 pool + bf16 hi/lo split, padded [b][35][35][32] ----------------
__global__ __launch_bounds__(256) void pool1b_k(const float* __restrict__ c1,
                                                ushort_t* __restrict__ p1h,
                                                ushort_t* __restrict__ p1l) {
    int b_l = blockIdx.x;
    int pr  = blockIdx.y;       // 0..34
    int tid = threadIdx.x;
    int py = pr - 2;
    bool irow = (py >= 0 && py < 31);
    __shared__ float sIn[3][64][32];
    if (irow) {
        int y0 = 2 * py;
        for (int i = tid; i < 3 * 64 * 32; i += 256) {
            int xx = i & 63; int r = (i >> 6) % 3; int ic = i / 192;
            float v = c1[(((size_t)b_l * 32 + ic) * 64 + (y0 + r)) * 64 + xx];
            sIn[r][xx][ic ^ (xx & 31)] = v;
        }
    }
    __syncthreads();
    size_t obase = ((size_t)b_l * 35 + pr) * 35 * 32;
    for (int j = tid; j < 35 * 32; j += 256) {
        int ic = j & 31, pc = j >> 5;
        int px = pc - 2;
        float m = 0.f;
        if (irow && px >= 0 && px < 31) {
            int x0 = 2 * px;
            #pragma unroll
            for (int r = 0; r < 3; ++r) {
                float a = fmaxf(fmaxf(sIn[r][x0][ic ^ (x0 & 31)],
                                      sIn[r][x0 + 1][ic ^ ((x0 + 1) & 31)]),
                                sIn[r][x0 + 2][ic ^ ((x0 + 2) & 31)]);
                m = fmaxf(m, a);
            }
        }
        ushort_t h = f2bf_rne(m);
        p1h[obase + j] = h;
        p1l[obase + j] = f2bf_rne(m - bf2f(h));
    }
}

// ---------------- prep_w2 ----------------
__global__ __launch_bounds__(256) void prep_w2_k(const float* __restrict__ w2,
                                                 ushort_t* __restrict__ w2p) {
    int idx = blockIdx.x * 256 + threadIdx.x;
    if (idx >= 25 * 64 * 32) return;
    int ic = idx & 31, oc = (idx >> 5) & 63, kk = idx >> 11;
    float w = w2[(size_t)(oc * 32 + ic) * 25 + kk];
    ushort_t h = f2bf_rne(w);
    w2p[(size_t)kk * 4096 + (idx & 2047)] = h;
    w2p[(size_t)kk * 4096 + 2048 + (idx & 2047)] = f2bf_rne(w - bf2f(h));
}

// ---------------- zero p2 padded buffers ----------------
__global__ __launch_bounds__(256) void zero_k(unsigned* __restrict__ p, int n) {
    int i = blockIdx.x * 256 + threadIdx.x;
    if (i < n) p[i] = 0u;
}

// ---------------- conv2 MFMA + fused bias/relu/pool2 -> p2 bf16 hi/lo padded ----------------
__global__ __launch_bounds__(256) void conv2_mfma_k(const ushort_t* __restrict__ p1h,
                                                    const ushort_t* __restrict__ p1l,
                                                    const ushort_t* __restrict__ w2p,
                                                    const float* __restrict__ b2,
                                                    ushort_t* __restrict__ p2h,
                                                    ushort_t* __restrict__ p2l) {
    int b_l = blockIdx.x;
    int yt  = blockIdx.y;
    int wave = threadIdx.x >> 6;
    int lane = threadIdx.x & 63;
    int wm = wave & 1, wy = wave >> 1;
    int y0 = yt * 8;
    int oc0 = wm * 32;
    int lr = lane & 15, lq = lane >> 4;
    int ybase = y0 + wy * 4;

    f32x4 acc[4][2][2];
    #pragma unroll
    for (int y = 0; y < 4; ++y)
        #pragma unroll
        for (int m = 0; m < 2; ++m)
            #pragma unroll
            for (int n = 0; n < 2; ++n)
                acc[y][m][n] = (f32x4)0.f;

    const ushort_t* p1hb = p1h + (size_t)b_l * 35 * 1120;
    const ushort_t* p1lb = p1l + (size_t)b_l * 35 * 1120;
    int aoff = (oc0 + lr) * 32 + lq * 8;

    #pragma unroll 1
    for (int kk = 0; kk < 25; ++kk) {
        int ky = kk / 5, kx = kk % 5;
        const ushort_t* wb = w2p + (size_t)kk * 4096;
        uv4 ah0 = *(const uv4*)(wb + aoff);
        uv4 ah1 = *(const uv4*)(wb + aoff + 512);
        uv4 al0 = *(const uv4*)(wb + 2048 + aoff);
        uv4 al1 = *(const uv4*)(wb + 2048 + aoff + 512);
        #pragma unroll
        for (int y = 0; y < 4; ++y) {
            int pr = ybase + y + ky; pr = pr > 34 ? 34 : pr;
            size_t ro = (size_t)pr * 1120;
            #pragma unroll
            for (int xt = 0; xt < 2; ++xt) {
                int pc = xt * 16 + lr + kx; pc = pc > 34 ? 34 : pc;
                size_t off = ro + (size_t)pc * 32 + lq * 8;
                uv4 bh = *(const uv4*)(p1hb + off);
                uv4 bl = *(const uv4*)(p1lb + off);
                MFMA16(acc[y][0][xt], ah0, bh);
                MFMA16(acc[y][1][xt], ah1, bh);
                MFMA16(acc[y][0][xt], ah0, bl);
                MFMA16(acc[y][1][xt], ah1, bl);
                MFMA16(acc[y][0][xt], al0, bh);
                MFMA16(acc[y][1][xt], al1, bh);
            }
        }
    }
    asm volatile("s_nop 7\n\ts_nop 7");

    float bias[2][4];
    #pragma unroll
    for (int m = 0; m < 2; ++m)
        #pragma unroll
        for (int j = 0; j < 4; ++j)
            bias[m][j] = b2[oc0 + m * 16 + lq * 4 + j];

    #pragma unroll
    for (int yp = 0; yp < 2; ++yp) {
        int yy = ybase + 2 * yp;
        if (yy + 1 > 30) continue;   // wave-uniform
        int py = yy >> 1;
        #pragma unroll
        for (int m = 0; m < 2; ++m)
            #pragma unroll
            for (int xt = 0; xt < 2; ++xt)
                #pragma unroll
                for (int j = 0; j < 4; ++j) {
                    float v = fmaxf(acc[2 * yp][m][xt][j], acc[2 * yp + 1][m][xt][j]);
                    float o = __shfl_xor(v, 1, 64);
                    v = fmaxf(fmaxf(v, o) + bias[m][j], 0.f);
                    int px = xt * 8 + (lr >> 1);
                    if (!(lane & 1) && px < 15) {
                        int oc = oc0 + m * 16 + lq * 4 + j;
                        size_t oo = (((size_t)b_l * 17 + py + 1) * 18 + px + 1) * 64 + oc;
                        ushort_t h = f2bf_rne(v);
                        p2h[oo] = h;
                        p2l[oo] = f2bf_rne(v - bf2f(h));
                    }
                }
    }
}

// ---------------- prep_w3: [ky*3+kx][ks][hl][oc128][kk32] ----------------
__global__ __launch_bounds__(256) void prep_w3_k(const float* __restrict__ w3,
                                                 ushort_t* __restrict__ w3p) {
    int idx = blockIdx.x * 256 + threadIdx.x;
    if (idx >= (int)W3P_ELEMS) return;
    int kk = idx & 31, oc = (idx >> 5) & 127, hl = (idx >> 12) & 1, ks = (idx >> 13) & 1, kxy = idx >> 14;
    int ky = kxy / 3, kx = kxy % 3;
    int ic = ks * 32 + kk;
    float w = w3[((size_t)(oc * 64 + ic) * 3 + ky) * 3 + kx];
    ushort_t h = f2bf_rne(w);
    w3p[idx] = hl ? f2bf_rne(w - bf2f(h)) : h;
}

// ---------------- conv3 MFMA: 3-pass hi/lo, +bias+relu -> c3 f32 ----------------
__global__ __launch_bounds__(256) void conv3_mfma_k(const ushort_t* __restrict__ p2h,
                                                    const ushort_t* __restrict__ p2l,
                                                    const ushort_t* __restrict__ w3p,
                                                    const float* __restrict__ b3,
                                                    float* __restrict__ c3) {
    int b_l = blockIdx.x;
    int oy0 = blockIdx.y * 5;
    int wave = threadIdx.x >> 6, lane = threadIdx.x & 63;
    int lr = lane & 15, lq = lane >> 4;
    int oc0 = wave * 32;
    const ushort_t* ph = p2h + (size_t)b_l * 17 * 18 * 64;
    const ushort_t* pl = p2l + (size_t)b_l * 17 * 18 * 64;
    f32x4 acc[5][2];
    #pragma unroll
    for (int y = 0; y < 5; ++y) { acc[y][0] = (f32x4)0.f; acc[y][1] = (f32x4)0.f; }

    #pragma unroll 1
    for (int ky = 0; ky < 3; ++ky)
        #pragma unroll 1
        for (int kx = 0; kx < 3; ++kx)
            #pragma unroll
            for (int ks = 0; ks < 2; ++ks) {
                const ushort_t* wb = w3p + (size_t)(((ky * 3 + kx) * 2 + ks) * 2) * 4096;
                uv4 ah0 = *(const uv4*)(wb + (oc0 + lr) * 32 + lq * 8);
                uv4 ah1 = *(const uv4*)(wb + (oc0 + 16 + lr) * 32 + lq * 8);
                uv4 al0 = *(const uv4*)(wb + 4096 + (oc0 + lr) * 32 + lq * 8);
                uv4 al1 = *(const uv4*)(wb + 4096 + (oc0 + 16 + lr) * 32 + lq * 8);
                #pragma unroll
                for (int yy = 0; yy < 5; ++yy) {
                    size_t off = ((size_t)(oy0 + yy + ky) * 18 + lr + kx) * 64 + ks * 32 + lq * 8;
                    uv4 bh = *(const uv4*)(ph + off);
                    uv4 bl = *(const uv4*)(pl + off);
                    MFMA16(acc[yy][0], ah0, bh);
                    MFMA16(acc[yy][1], ah1, bh);
                    MFMA16(acc[yy][0], ah0, bl);
                    MFMA16(acc[yy][1], ah1, bl);
                    MFMA16(acc[yy][0], al0, bh);
                    MFMA16(acc[yy][1], al1, bh);
                }
            }
    asm volatile("s_nop 7\n\ts_nop 7");
    if (lr < 15) {
        #pragma unroll
        for (int yy = 0; yy < 5; ++yy)
            #pragma unroll
            for (int m = 0; m < 2; ++m)
                #pragma unroll
                for (int j = 0; j < 4; ++j) {
                    int oc = oc0 + m * 16 + lq * 4 + j;
                    float v = fmaxf(acc[yy][m][j] + b3[oc], 0.f);
                    c3[((size_t)b_l * 128 + oc) * 225 + (oy0 + yy) * 15 + lr] = v;
                }
    }
}

// ---------------- pool3 + mean ----------------
__global__ __launch_bounds__(256) void pool3mean_k(const float* __restrict__ c3,
                                                   float* __restrict__ feat, int b0) {
    int idx = blockIdx.x * 256 + threadIdx.x;
    if (idx >= CHUNK * 128) return;
    int oc = idx & 127, b_l = idx >> 7;
    const float* base = c3 + (size_t)idx * 225;
    float s = 0.f;
    #pragma unroll
    for (int py = 0; py < 7; ++py)
        #pragma unroll
        for (int px = 0; px < 7; ++px) {
            float m = fmaxf(fmaxf(base[(2 * py) * 15 + 2 * px],     base[(2 * py) * 15 + 2 * px + 1]),
                            fmaxf(base[(2 * py + 1) * 15 + 2 * px], base[(2 * py + 1) * 15 + 2 * px + 1]));
            s += m;
        }
    feat[(size_t)(b0 + b_l) * 128 + oc] = s * (1.f / 49.f);
}

// ---------------- fc1 (relu) + fc2 ----------------
__global__ __launch_bounds__(128) void fc_k(const float* __restrict__ feat,
                                            const float* __restrict__ fw1,
                                            const float* __restrict__ fb1,
                                            const float* __restrict__ fw2,
                                            const float* __restrict__ fb2,
                                            float* __restrict__ out) {
    __shared__ float sF[128];
    __shared__ float sH[128];
    int b = blockIdx.x, tid = threadIdx.x;
    sF[tid] = feat[(size_t)b * 128 + tid];
    __syncthreads();
    const float4* wrow = (const float4*)(fw1 + (size_t)tid * 128);
    float s = fb1[tid];
    #pragma unroll
    for (int i = 0; i < 32; ++i) {
        float4 w = wrow[i];
        s = fmaf(w.x, sF[4 * i], s);
        s = fmaf(w.y, sF[4 * i + 1], s);
        s = fmaf(w.z, sF[4 * i + 2], s);
        s = fmaf(w.w, sF[4 * i + 3], s);
    }
    sH[tid] = fmaxf(s, 0.f);
    __syncthreads();
    if (tid < 5) {
        const float* w2r = fw2 + (size_t)tid * 128;
        float s2 = fb2[tid];
        for (int i = 0; i < 128; ++i) s2 = fmaf(w2r[i], sH[i], s2);
        out[(size_t)b * 5 + tid] = s2;
    }
}

// ---------------- launch ----------------
extern "C" void kernel_launch(void* const* d_in, const int* in_sizes, int n_in,
                              void* d_out, int out_size, void* d_ws, size_t ws_size,
                              hipStream_t stream) {
    const int*   x   = (const int*)d_in[0];
    const float* w1  = (const float*)d_in[1];
    const float* b1  = (const float*)d_in[2];
    const float* w2  = (const float*)d_in[3];
    const float* b2  = (const float*)d_in[4];
    const float* w3  = (const float*)d_in[5];
    const float* b3  = (const float*)d_in[6];
    const float* fw1 = (const float*)d_in[7];
    const float* fb1 = (const float*)d_in[8];
    const float* fw2 = (const float*)d_in[9];
    const float* fb2 = (const float*)d_in[10];
    float* out = (float*)d_out;

    float* ws   = (float*)d_ws;
    float* c1_c = ws;
    float* c3_c = c1_c + C1_ELEMS;
    float* feat = c3_c + C3_ELEMS;
    ushort_t* tb  = (ushort_t*)(feat + FEAT_ELEMS);
    ushort_t* p1h = tb + TB_ELEMS;
    ushort_t* p1l = p1h + P1P_ELEMS;
    ushort_t* p2h = p1l + P1P_ELEMS;
    ushort_t* p2l = p2h + P2P_ELEMS;
    ushort_t* w1p = p2l + P2P_ELEMS;
    ushort_t* w2p = w1p + W1P_ELEMS;
    ushort_t* w3p = w2p + W2P_ELEMS;

    prep_w1_k<<<((int)W1P_ELEMS + 255) / 256, 256, 0, stream>>>(w1, w1p);
    prep_w2_k<<<(25 * 64 * 32 + 255) / 256, 256, 0, stream>>>(w2, w2p);
    prep_w3_k<<<((int)W3P_ELEMS + 255) / 256, 256, 0, stream>>>(w3, w3p);

    int p2_uints = (int)(2 * P2P_ELEMS / 2);
    for (int ch = 0; ch < NCHUNK; ++ch) {
        int b0 = ch * CHUNK;
        rasterize_bf_k<<<dim3(CHUNK, 8), 256, 0, stream>>>(x, tb, b0);
        conv1_mfma_k<<<dim3(CHUNK, 4), 256, 0, stream>>>(tb, w1p, b1, c1_c);
        pool1b_k<<<dim3(CHUNK, 35), 256, 0, stream>>>(c1_c, p1h, p1l);
        zero_k<<<(p2_uints + 255) / 256, 256, 0, stream>>>((unsigned*)p2h, p2_uints);
        conv2_mfma_k<<<dim3(CHUNK, 4), 256, 0, stream>>>(p1h, p1l, w2p, b2, p2h, p2l);
        conv3_mfma_k<<<dim3(CHUNK, 3), 256, 0, stream>>>(p2h, p2l, w3p, b3, c3_c);
        pool3mean_k<<<(CHUNK * 128 + 255) / 256, 256, 0, stream>>>(c3_c, feat, b0);
    }
    fc_k<<<Bfull, 128, 0, stream>>>(feat, fw1, fb1, fw2, fb2, out);
}

// Round 7
// 803.270 us; speedup vs baseline: 2.5343x; 1.0832x over previous
//
#include <hip/hip_runtime.h>
#include <cstddef>

typedef unsigned short ushort_t;
typedef unsigned uv4 __attribute__((ext_vector_type(4)));
typedef unsigned uv2 __attribute__((ext_vector_type(2)));
typedef float f32x4 __attribute__((ext_vector_type(4)));

// ---------------- problem constants ----------------
constexpr int Bfull = 512;
constexpr int F = 4, O = 10;

// per-image byte sizes (all 16B-aligned)
constexpr size_t TB_B  = (size_t)136 * 136 * 4 * 2;   // 147,968
constexpr size_t C1_B  = (size_t)32 * 64 * 64 * 4;    // 524,288
constexpr size_t P1_B  = (size_t)35 * 35 * 32 * 2;    // 78,400 (each of h,l)
constexpr size_t P2_B  = (size_t)17 * 18 * 64 * 2;    // 39,168 (each of h,l)
constexpr size_t C3_B  = (size_t)128 * 15 * 15 * 4;   // 115,200
constexpr size_t FEAT_B = (size_t)Bfull * 128 * 4;    // 262,144
constexpr size_t W1P_ELEMS = (size_t)7 * 4 * 16 * 32;        // 28672 ushort
constexpr size_t W2P_ELEMS = (size_t)25 * 2 * 64 * 32;       // 102400 ushort
constexpr size_t W3P_ELEMS = (size_t)9 * 2 * 2 * 128 * 32;   // 147456 ushort

__device__ __forceinline__ ushort_t f2bf_rne(float x) {
    unsigned u = __builtin_bit_cast(unsigned, x);
    unsigned r = (u + 0x7FFFu + ((u >> 16) & 1u)) >> 16;
    return (ushort_t)r;
}
__device__ __forceinline__ float bf2f(ushort_t b) {
    return __builtin_bit_cast(float, (unsigned)b << 16);
}

#define MFMA16(acc, a, b) \
    asm("v_mfma_f32_16x16x32_bf16 %0, %1, %2, %0" : "+v"(acc) : "v"(a), "v"(b))

// ---------------- rasterize -> padded bf16 [b][136r][136c][4ic] ----------------
__global__ __launch_bounds__(256) void rasterize_bf_k(const int* __restrict__ x,
                                                      ushort_t* __restrict__ tb, int b0) {
    int b_l = blockIdx.x;
    int rg  = blockIdx.y;             // row-group 0..7
    int b = b0 + b_l;
    __shared__ int pts[F][O][2];
    __shared__ int prm[F][24];
    int tid = threadIdx.x;
    if (tid < F * O * 2)
        ((int*)pts)[tid] = x[(size_t)b * F * O * 2 + tid];
    __syncthreads();
    if (tid < F) {
        int f = tid;
        int dX = 64 + pts[f][O - 1][0];
        int dY = 64 - pts[f][O - 1][1];
        prm[f][0] = dX; prm[f][1] = dY;
        prm[f][2] = dX >= 64 ? 64 : dX + 1; prm[f][3] = dX >= 64 ? dX - 1 : 64;
        prm[f][4] = dY >= 64 ? 64 : dY + 1; prm[f][5] = dY >= 64 ? dY - 1 : 64;
        for (int k = 0; k < O - 1; ++k) {
            prm[f][6 + k]  = (pts[f][k][0] + 64) % 127;
            prm[f][15 + k] = (64 - pts[f][k][1]) % 127;
        }
    }
    __syncthreads();
    ushort_t* outp = tb + (size_t)b_l * 136 * 136 * 4;
    int r0 = rg * 17;
    for (int i = tid; i < 17 * 136; i += 256) {
        int r = r0 + i / 136, c = i % 136;
        int y = r - 3, xx = c - 3;
        unsigned pack0 = 0, pack1 = 0;
        if (y >= 0 && y < 128 && xx >= 0 && xx < 128) {
            bool ctr9 = (y >= 63 && y <= 65 && xx >= 63 && xx <= 65);
            bool ctr1 = (y == 64 && xx == 64);
            #pragma unroll
            for (int f = 0; f < 4; ++f) {
                unsigned bf;
                if (ctr1) bf = 0x3F80u;
                else if (ctr9) bf = 0x3F00u;
                else {
                    int dX = prm[f][0];
                    bool mX = (xx >= prm[f][2]) && (xx <= prm[f][3]);
                    bool mY = (y >= prm[f][4]) && (y <= prm[f][5]);
                    bf = ((mX && y == 64) || (mY && xx == dX)) ? 0xBF80u : 0u;
                }
                if (f & 1) { if (f >> 1) pack1 |= bf << 16; else pack0 |= bf << 16; }
                else       { if (f >> 1) pack1 |= bf;       else pack0 |= bf; }
            }
        }
        uv2 pk; pk.x = pack0; pk.y = pack1;
        *(uv2*)(outp + ((size_t)r * 136 + c) * 4) = pk;
    }
    __syncthreads();
    if (tid < 4) {
        int f = tid;
        int r1 = r0 + 17;
        for (int k = 0; k < O - 1; ++k) {
            int a = prm[f][6 + k] + 3, bb = prm[f][15 + k] + 3;
            #pragma unroll
            for (int dy = -1; dy <= 1; ++dy) {
                int rr = bb + dy;
                if (rr >= r0 && rr < r1) {
                    ushort_t* rowp = outp + ((size_t)rr * 136 + a - 1) * 4 + f;
                    rowp[0] = 0x3F00u; rowp[4] = 0x3F00u; rowp[8] = 0x3F00u;
                }
            }
            if (bb >= r0 && bb < r1) outp[((size_t)bb * 136 + a) * 4 + f] = 0x3F80u;
        }
    }
}

// ---------------- prep_w1 ----------------
__global__ __launch_bounds__(256) void prep_w1_k(const float* __restrict__ w1,
                                                 ushort_t* __restrict__ w1p) {
    int idx = blockIdx.x * 256 + threadIdx.x;
    if (idx >= (int)W1P_ELEMS) return;
    int k = idx & 31, lr = (idx >> 5) & 15, slot = (idx >> 9) & 3, ky = idx >> 11;
    int hl = slot & 1, m = slot >> 1;
    int kx = k >> 2, ic = k & 3;
    int oc = m * 16 + lr;
    float w = (kx < 7) ? w1[((oc * 4 + ic) * 7 + ky) * 7 + kx] : 0.f;
    ushort_t h = f2bf_rne(w);
    w1p[idx] = hl ? f2bf_rne(w - bf2f(h)) : h;
}

// ---------------- conv1 MFMA ----------------
__global__ __launch_bounds__(256) void conv1_mfma_k(const ushort_t* __restrict__ tb,
                                                    const ushort_t* __restrict__ w1p,
                                                    const float* __restrict__ b1,
                                                    float* __restrict__ c1) {
    int b_l = blockIdx.x;
    int oyt = blockIdx.y;
    int wave = threadIdx.x >> 6, lane = threadIdx.x & 63;
    int lr = lane & 15, lq = lane >> 4;
    const ushort_t* tbb = tb + (size_t)b_l * 136 * 136 * 4;
    int aoff = lr * 32 + lq * 8;
    float bias[2][4];
    #pragma unroll
    for (int m = 0; m < 2; ++m)
        #pragma unroll
        for (int j = 0; j < 4; ++j)
            bias[m][j] = b1[m * 16 + lq * 4 + j];
    int oybase = oyt * 16 + wave * 4;
    #pragma unroll 1
    for (int yy = 0; yy < 4; ++yy) {
        int oy = oybase + yy;
        f32x4 acc[2][4];
        #pragma unroll
        for (int m = 0; m < 2; ++m)
            #pragma unroll
            for (int xt = 0; xt < 4; ++xt)
                acc[m][xt] = (f32x4)0.f;
        #pragma unroll
        for (int ky = 0; ky < 7; ++ky) {
            const ushort_t* wb = w1p + (size_t)ky * 2048;
            uv4 ah0 = *(const uv4*)(wb + aoff);
            uv4 al0 = *(const uv4*)(wb + 512 + aoff);
            uv4 ah1 = *(const uv4*)(wb + 1024 + aoff);
            uv4 al1 = *(const uv4*)(wb + 1536 + aoff);
            const ushort_t* rb = tbb + (size_t)(2 * oy + ky) * (136 * 4);
            #pragma unroll
            for (int xt = 0; xt < 4; ++xt) {
                uv4 bv = *(const uv4*)(rb + (size_t)(2 * (xt * 16 + lr) + 2 * lq) * 4);
                MFMA16(acc[0][xt], ah0, bv);
                MFMA16(acc[1][xt], ah1, bv);
                MFMA16(acc[0][xt], al0, bv);
                MFMA16(acc[1][xt], al1, bv);
            }
        }
        asm volatile("s_nop 7\n\ts_nop 7");
        #pragma unroll
        for (int m = 0; m < 2; ++m)
            #pragma unroll
            for (int xt = 0; xt < 4; ++xt)
                #pragma unroll
                for (int j = 0; j < 4; ++j) {
                    int oc = m * 16 + lq * 4 + j;
                    float v = fmaxf(acc[m][xt][j] + bias[m][j], 0.f);
                    c1[(((size_t)b_l * 32 + oc) * 64 + oy) * 64 + xt * 16 + lr] = v;
                }
    }
}

// ---------------- pool1b ----------------
__global__ __launch_bounds__(256) void pool1b_k(const float* __restrict__ c1,
                                                ushort_t* __restrict__ p1h,
                                                ushort_t* __restrict__ p1l) {
    int b_l = blockIdx.x;
    int pr  = blockIdx.y;       // 0..34
    int tid = threadIdx.x;
    int py = pr - 2;
    bool irow = (py >= 0 && py < 31);
    __shared__ float sIn[3][64][32];
    if (irow) {
        int y0 = 2 * py;
        for (int i = tid; i < 3 * 64 * 32; i += 256) {
            int xx = i & 63; int r = (i >> 6) % 3; int ic = i / 192;
            float v = c1[(((size_t)b_l * 32 + ic) * 64 + (y0 + r)) * 64 + xx];
            sIn[r][xx][ic ^ (xx & 31)] = v;
        }
    }
    __syncthreads();
    size_t obase = ((size_t)b_l * 35 + pr) * 35 * 32;
    for (int j = tid; j < 35 * 32; j += 256) {
        int ic = j & 31, pc = j >> 5;
        int px = pc - 2;
        float m = 0.f;
        if (irow && px >= 0 && px < 31) {
            int x0 = 2 * px;
            #pragma unroll
            for (int r = 0; r < 3; ++r) {
                float a = fmaxf(fmaxf(sIn[r][x0][ic ^ (x0 & 31)],
                                      sIn[r][x0 + 1][ic ^ ((x0 + 1) & 31)]),
                                sIn[r][x0 + 2][ic ^ ((x0 + 2) & 31)]);
                m = fmaxf(m, a);
            }
        }
        ushort_t h = f2bf_rne(m);
        p1h[obase + j] = h;
        p1l[obase + j] = f2bf_rne(m - bf2f(h));
    }
}

// ---------------- prep_w2 ----------------
__global__ __launch_bounds__(256) void prep_w2_k(const float* __restrict__ w2,
                                                 ushort_t* __restrict__ w2p) {
    int idx = blockIdx.x * 256 + threadIdx.x;
    if (idx >= 25 * 64 * 32) return;
    int ic = idx & 31, oc = (idx >> 5) & 63, kk = idx >> 11;
    float w = w2[(size_t)(oc * 32 + ic) * 25 + kk];
    ushort_t h = f2bf_rne(w);
    w2p[(size_t)kk * 4096 + (idx & 2047)] = h;
    w2p[(size_t)kk * 4096 + 2048 + (idx & 2047)] = f2bf_rne(w - bf2f(h));
}

// ---------------- zero ----------------
__global__ __launch_bounds__(256) void zero_k(unsigned* __restrict__ p, int n) {
    int i = blockIdx.x * 256 + threadIdx.x;
    if (i < n) p[i] = 0u;
}

// ---------------- conv2 MFMA + fused bias/relu/pool2 ----------------
__global__ __launch_bounds__(256) void conv2_mfma_k(const ushort_t* __restrict__ p1h,
                                                    const ushort_t* __restrict__ p1l,
                                                    const ushort_t* __restrict__ w2p,
                                                    const float* __restrict__ b2,
                                                    ushort_t* __restrict__ p2h,
                                                    ushort_t* __restrict__ p2l) {
    int b_l = blockIdx.x;
    int yt  = blockIdx.y;
    int wave = threadIdx.x >> 6;
    int lane = threadIdx.x & 63;
    int wm = wave & 1, wy = wave >> 1;
    int y0 = yt * 8;
    int oc0 = wm * 32;
    int lr = lane & 15, lq = lane >> 4;
    int ybase = y0 + wy * 4;

    f32x4 acc[4][2][2];
    #pragma unroll
    for (int y = 0; y < 4; ++y)
        #pragma unroll
        for (int m = 0; m < 2; ++m)
            #pragma unroll
            for (int n = 0; n < 2; ++n)
                acc[y][m][n] = (f32x4)0.f;

    const ushort_t* p1hb = p1h + (size_t)b_l * 35 * 1120;
    const ushort_t* p1lb = p1l + (size_t)b_l * 35 * 1120;
    int aoff = (oc0 + lr) * 32 + lq * 8;

    #pragma unroll 1
    for (int kk = 0; kk < 25; ++kk) {
        int ky = kk / 5, kx = kk % 5;
        const ushort_t* wb = w2p + (size_t)kk * 4096;
        uv4 ah0 = *(const uv4*)(wb + aoff);
        uv4 ah1 = *(const uv4*)(wb + aoff + 512);
        uv4 al0 = *(const uv4*)(wb + 2048 + aoff);
        uv4 al1 = *(const uv4*)(wb + 2048 + aoff + 512);
        #pragma unroll
        for (int y = 0; y < 4; ++y) {
            int pr = ybase + y + ky; pr = pr > 34 ? 34 : pr;
            size_t ro = (size_t)pr * 1120;
            #pragma unroll
            for (int xt = 0; xt < 2; ++xt) {
                int pc = xt * 16 + lr + kx; pc = pc > 34 ? 34 : pc;
                size_t off = ro + (size_t)pc * 32 + lq * 8;
                uv4 bh = *(const uv4*)(p1hb + off);
                uv4 bl = *(const uv4*)(p1lb + off);
                MFMA16(acc[y][0][xt], ah0, bh);
                MFMA16(acc[y][1][xt], ah1, bh);
                MFMA16(acc[y][0][xt], ah0, bl);
                MFMA16(acc[y][1][xt], ah1, bl);
                MFMA16(acc[y][0][xt], al0, bh);
                MFMA16(acc[y][1][xt], al1, bh);
            }
        }
    }
    asm volatile("s_nop 7\n\ts_nop 7");

    float bias[2][4];
    #pragma unroll
    for (int m = 0; m < 2; ++m)
        #pragma unroll
        for (int j = 0; j < 4; ++j)
            bias[m][j] = b2[oc0 + m * 16 + lq * 4 + j];

    #pragma unroll
    for (int yp = 0; yp < 2; ++yp) {
        int yy = ybase + 2 * yp;
        if (yy + 1 > 30) continue;   // wave-uniform
        int py = yy >> 1;
        #pragma unroll
        for (int m = 0; m < 2; ++m)
            #pragma unroll
            for (int xt = 0; xt < 2; ++xt)
                #pragma unroll
                for (int j = 0; j < 4; ++j) {
                    float v = fmaxf(acc[2 * yp][m][xt][j], acc[2 * yp + 1][m][xt][j]);
                    float o = __shfl_xor(v, 1, 64);
                    v = fmaxf(fmaxf(v, o) + bias[m][j], 0.f);
                    int px = xt * 8 + (lr >> 1);
                    if (!(lane & 1) && px < 15) {
                        int oc = oc0 + m * 16 + lq * 4 + j;
                        size_t oo = (((size_t)b_l * 17 + py + 1) * 18 + px + 1) * 64 + oc;
                        ushort_t h = f2bf_rne(v);
                        p2h[oo] = h;
                        p2l[oo] = f2bf_rne(v - bf2f(h));
                    }
                }
    }
}

// ---------------- prep_w3 ----------------
__global__ __launch_bounds__(256) void prep_w3_k(const float* __restrict__ w3,
                                                 ushort_t* __restrict__ w3p) {
    int idx = blockIdx.x * 256 + threadIdx.x;
    if (idx >= (int)W3P_ELEMS) return;
    int kk = idx & 31, oc = (idx >> 5) & 127, hl = (idx >> 12) & 1, ks = (idx >> 13) & 1, kxy = idx >> 14;
    int ky = kxy / 3, kx = kxy % 3;
    int ic = ks * 32 + kk;
    float w = w3[((size_t)(oc * 64 + ic) * 3 + ky) * 3 + kx];
    ushort_t h = f2bf_rne(w);
    w3p[idx] = hl ? f2bf_rne(w - bf2f(h)) : h;
}

// ---------------- conv3 MFMA ----------------
__global__ __launch_bounds__(256) void conv3_mfma_k(const ushort_t* __restrict__ p2h,
                                                    const ushort_t* __restrict__ p2l,
                                                    const ushort_t* __restrict__ w3p,
                                                    const float* __restrict__ b3,
                                                    float* __restrict__ c3) {
    int b_l = blockIdx.x;
    int oy0 = blockIdx.y * 5;
    int wave = threadIdx.x >> 6, lane = threadIdx.x & 63;
    int lr = lane & 15, lq = lane >> 4;
    int oc0 = wave * 32;
    const ushort_t* ph = p2h + (size_t)b_l * 17 * 18 * 64;
    const ushort_t* pl = p2l + (size_t)b_l * 17 * 18 * 64;
    f32x4 acc[5][2];
    #pragma unroll
    for (int y = 0; y < 5; ++y) { acc[y][0] = (f32x4)0.f; acc[y][1] = (f32x4)0.f; }

    #pragma unroll 1
    for (int ky = 0; ky < 3; ++ky)
        #pragma unroll 1
        for (int kx = 0; kx < 3; ++kx)
            #pragma unroll
            for (int ks = 0; ks < 2; ++ks) {
                const ushort_t* wb = w3p + (size_t)(((ky * 3 + kx) * 2 + ks) * 2) * 4096;
                uv4 ah0 = *(const uv4*)(wb + (oc0 + lr) * 32 + lq * 8);
                uv4 ah1 = *(const uv4*)(wb + (oc0 + 16 + lr) * 32 + lq * 8);
                uv4 al0 = *(const uv4*)(wb + 4096 + (oc0 + lr) * 32 + lq * 8);
                uv4 al1 = *(const uv4*)(wb + 4096 + (oc0 + 16 + lr) * 32 + lq * 8);
                #pragma unroll
                for (int yy = 0; yy < 5; ++yy) {
                    size_t off = ((size_t)(oy0 + yy + ky) * 18 + lr + kx) * 64 + ks * 32 + lq * 8;
                    uv4 bh = *(const uv4*)(ph + off);
                    uv4 bl = *(const uv4*)(pl + off);
                    MFMA16(acc[yy][0], ah0, bh);
                    MFMA16(acc[yy][1], ah1, bh);
                    MFMA16(acc[yy][0], ah0, bl);
                    MFMA16(acc[yy][1], ah1, bl);
                    MFMA16(acc[yy][0], al0, bh);
                    MFMA16(acc[yy][1], al1, bh);
                }
            }
    asm volatile("s_nop 7\n\ts_nop 7");
    if (lr < 15) {
        #pragma unroll
        for (int yy = 0; yy < 5; ++yy)
            #pragma unroll
            for (int m = 0; m < 2; ++m)
                #pragma unroll
                for (int j = 0; j < 4; ++j) {
                    int oc = oc0 + m * 16 + lq * 4 + j;
                    float v = fmaxf(acc[yy][m][j] + b3[oc], 0.f);
                    c3[((size_t)b_l * 128 + oc) * 225 + (oy0 + yy) * 15 + lr] = v;
                }
    }
}

// ---------------- pool3 + mean ----------------
__global__ __launch_bounds__(256) void pool3mean_k(const float* __restrict__ c3,
                                                   float* __restrict__ feat, int b0, int n) {
    int idx = blockIdx.x * 256 + threadIdx.x;
    if (idx >= n) return;
    int oc = idx & 127, b_l = idx >> 7;
    const float* base = c3 + (size_t)idx * 225;
    float s = 0.f;
    #pragma unroll
    for (int py = 0; py < 7; ++py)
        #pragma unroll
        for (int px = 0; px < 7; ++px) {
            float m = fmaxf(fmaxf(base[(2 * py) * 15 + 2 * px],     base[(2 * py) * 15 + 2 * px + 1]),
                            fmaxf(base[(2 * py + 1) * 15 + 2 * px], base[(2 * py + 1) * 15 + 2 * px + 1]));
            s += m;
        }
    feat[(size_t)(b0 + b_l) * 128 + oc] = s * (1.f / 49.f);
}

// ---------------- fc1 (relu) + fc2 ----------------
__global__ __launch_bounds__(128) void fc_k(const float* __restrict__ feat,
                                            const float* __restrict__ fw1,
                                            const float* __restrict__ fb1,
                                            const float* __restrict__ fw2,
                                            const float* __restrict__ fb2,
                                            float* __restrict__ out) {
    __shared__ float sF[128];
    __shared__ float sH[128];
    int b = blockIdx.x, tid = threadIdx.x;
    sF[tid] = feat[(size_t)b * 128 + tid];
    __syncthreads();
    const float4* wrow = (const float4*)(fw1 + (size_t)tid * 128);
    float s = fb1[tid];
    #pragma unroll
    for (int i = 0; i < 32; ++i) {
        float4 w = wrow[i];
        s = fmaf(w.x, sF[4 * i], s);
        s = fmaf(w.y, sF[4 * i + 1], s);
        s = fmaf(w.z, sF[4 * i + 2], s);
        s = fmaf(w.w, sF[4 * i + 3], s);
    }
    sH[tid] = fmaxf(s, 0.f);
    __syncthreads();
    if (tid < 5) {
        const float* w2r = fw2 + (size_t)tid * 128;
        float s2 = fb2[tid];
        for (int i = 0; i < 128; ++i) s2 = fmaf(w2r[i], sH[i], s2);
        out[(size_t)b * 5 + tid] = s2;
    }
}

// ---------------- launch ----------------
extern "C" void kernel_launch(void* const* d_in, const int* in_sizes, int n_in,
                              void* d_out, int out_size, void* d_ws, size_t ws_size,
                              hipStream_t stream) {
    const int*   x   = (const int*)d_in[0];
    const float* w1  = (const float*)d_in[1];
    const float* b1  = (const float*)d_in[2];
    const float* w2  = (const float*)d_in[3];
    const float* b2  = (const float*)d_in[4];
    const float* w3  = (const float*)d_in[5];
    const float* b3  = (const float*)d_in[6];
    const float* fw1 = (const float*)d_in[7];
    const float* fb1 = (const float*)d_in[8];
    const float* fw2 = (const float*)d_in[9];
    const float* fb2 = (const float*)d_in[10];
    float* out = (float*)d_out;

    // choose per-dispatch batch NB by available workspace (prefer full batch)
    const size_t per_img = C1_B + C3_B + TB_B + 2 * P1_B + 2 * P2_B;   // 1,022,592 B
    const size_t fixed_b = FEAT_B + (W1P_ELEMS + W2P_ELEMS + W3P_ELEMS) * 2 + 1024;
    int NB = Bfull;
    while (NB > 128 && fixed_b + per_img * (size_t)NB > ws_size) NB >>= 1;

    char* base = (char*)d_ws;
    float* c1_c = (float*)base;                         base += (size_t)NB * C1_B;
    float* c3_c = (float*)base;                         base += (size_t)NB * C3_B;
    float* feat = (float*)base;                         base += FEAT_B;
    ushort_t* tb  = (ushort_t*)base;                    base += (size_t)NB * TB_B;
    ushort_t* p1h = (ushort_t*)base;                    base += (size_t)NB * P1_B;
    ushort_t* p1l = (ushort_t*)base;                    base += (size_t)NB * P1_B;
    ushort_t* p2h = (ushort_t*)base;                    base += (size_t)NB * P2_B;
    ushort_t* p2l = (ushort_t*)base;                    base += (size_t)NB * P2_B;
    ushort_t* w1p = (ushort_t*)base;                    base += W1P_ELEMS * 2;
    ushort_t* w2p = (ushort_t*)base;                    base += W2P_ELEMS * 2;
    ushort_t* w3p = (ushort_t*)base;

    prep_w1_k<<<((int)W1P_ELEMS + 255) / 256, 256, 0, stream>>>(w1, w1p);
    prep_w2_k<<<(25 * 64 * 32 + 255) / 256, 256, 0, stream>>>(w2, w2p);
    prep_w3_k<<<((int)W3P_ELEMS + 255) / 256, 256, 0, stream>>>(w3, w3p);

    const int nchunk = Bfull / NB;
    const int p2_uints = NB * (17 * 18 * 64 * 2 / 2);   // h+l planes as uints
    for (int ch = 0; ch < nchunk; ++ch) {
        int b0 = ch * NB;
        rasterize_bf_k<<<dim3(NB, 8), 256, 0, stream>>>(x, tb, b0);
        conv1_mfma_k<<<dim3(NB, 4), 256, 0, stream>>>(tb, w1p, b1, c1_c);
        pool1b_k<<<dim3(NB, 35), 256, 0, stream>>>(c1_c, p1h, p1l);
        zero_k<<<(p2_uints + 255) / 256, 256, 0, stream>>>((unsigned*)p2h, p2_uints);
        conv2_mfma_k<<<dim3(NB, 4), 256, 0, stream>>>(p1h, p1l, w2p, b2, p2h, p2l);
        conv3_mfma_k<<<dim3(NB, 3), 256, 0, stream>>>(p2h, p2l, w3p, b3, c3_c);
        pool3mean_k<<<(NB * 128 + 255) / 256, 256, 0, stream>>>(c3_c, feat, b0, NB * 128);
    }
    fc_k<<<Bfull, 128, 0, stream>>>(feat, fw1, fb1, fw2, fb2, out);
}

// Round 8
// 598.867 us; speedup vs baseline: 3.3993x; 1.3413x over previous
//
#include <hip/hip_runtime.h>
#include <cstddef>

typedef unsigned short ushort_t;
typedef unsigned uv4 __attribute__((ext_vector_type(4)));
typedef unsigned uv2 __attribute__((ext_vector_type(2)));
typedef float f32x4 __attribute__((ext_vector_type(4)));

// ---------------- problem constants ----------------
constexpr int Bfull = 512;
constexpr int F = 4, O = 10;

// per-image byte sizes (all 16B-aligned)
constexpr size_t TB_B  = (size_t)136 * 136 * 4 * 2;   // 147,968
constexpr size_t C1_B  = (size_t)64 * 64 * 32 * 4;    // 524,288 (uint h|l<<16, [y][x][oc])
constexpr size_t P1_B  = (size_t)35 * 35 * 32 * 2;    // 78,400 (each of h,l)
constexpr size_t P2_B  = (size_t)17 * 18 * 64 * 2;    // 39,168 (each of h,l)
constexpr size_t C3_B  = (size_t)128 * 15 * 15 * 4;   // 115,200
constexpr size_t FEAT_B = (size_t)Bfull * 128 * 4;    // 262,144
constexpr size_t W1P_ELEMS = (size_t)7 * 4 * 16 * 32;        // 28672 ushort
constexpr size_t W2P_ELEMS = (size_t)25 * 2 * 64 * 32;       // 102400 ushort
constexpr size_t W3P_ELEMS = (size_t)9 * 2 * 2 * 128 * 32;   // 147456 ushort

__device__ __forceinline__ ushort_t f2bf_rne(float x) {
    unsigned u = __builtin_bit_cast(unsigned, x);
    unsigned r = (u + 0x7FFFu + ((u >> 16) & 1u)) >> 16;
    return (ushort_t)r;
}
__device__ __forceinline__ float bf2f(ushort_t b) {
    return __builtin_bit_cast(float, (unsigned)b << 16);
}

#define MFMA16(acc, a, b) \
    asm("v_mfma_f32_16x16x32_bf16 %0, %1, %2, %0" : "+v"(acc) : "v"(a), "v"(b))

// ---------------- rasterize -> padded bf16 [b][136r][136c][4ic] ----------------
__global__ __launch_bounds__(256) void rasterize_bf_k(const int* __restrict__ x,
                                                      ushort_t* __restrict__ tb, int b0) {
    int b_l = blockIdx.x;
    int rg  = blockIdx.y;             // row-group 0..7
    int b = b0 + b_l;
    __shared__ int pts[F][O][2];
    __shared__ int prm[F][24];
    int tid = threadIdx.x;
    if (tid < F * O * 2)
        ((int*)pts)[tid] = x[(size_t)b * F * O * 2 + tid];
    __syncthreads();
    if (tid < F) {
        int f = tid;
        int dX = 64 + pts[f][O - 1][0];
        int dY = 64 - pts[f][O - 1][1];
        prm[f][0] = dX; prm[f][1] = dY;
        prm[f][2] = dX >= 64 ? 64 : dX + 1; prm[f][3] = dX >= 64 ? dX - 1 : 64;
        prm[f][4] = dY >= 64 ? 64 : dY + 1; prm[f][5] = dY >= 64 ? dY - 1 : 64;
        for (int k = 0; k < O - 1; ++k) {
            prm[f][6 + k]  = (pts[f][k][0] + 64) % 127;
            prm[f][15 + k] = (64 - pts[f][k][1]) % 127;
        }
    }
    __syncthreads();
    ushort_t* outp = tb + (size_t)b_l * 136 * 136 * 4;
    int r0 = rg * 17;
    for (int i = tid; i < 17 * 136; i += 256) {
        int r = r0 + i / 136, c = i % 136;
        int y = r - 3, xx = c - 3;
        unsigned pack0 = 0, pack1 = 0;
        if (y >= 0 && y < 128 && xx >= 0 && xx < 128) {
            bool ctr9 = (y >= 63 && y <= 65 && xx >= 63 && xx <= 65);
            bool ctr1 = (y == 64 && xx == 64);
            #pragma unroll
            for (int f = 0; f < 4; ++f) {
                unsigned bf;
                if (ctr1) bf = 0x3F80u;
                else if (ctr9) bf = 0x3F00u;
                else {
                    int dX = prm[f][0];
                    bool mX = (xx >= prm[f][2]) && (xx <= prm[f][3]);
                    bool mY = (y >= prm[f][4]) && (y <= prm[f][5]);
                    bf = ((mX && y == 64) || (mY && xx == dX)) ? 0xBF80u : 0u;
                }
                if (f & 1) { if (f >> 1) pack1 |= bf << 16; else pack0 |= bf << 16; }
                else       { if (f >> 1) pack1 |= bf;       else pack0 |= bf; }
            }
        }
        uv2 pk; pk.x = pack0; pk.y = pack1;
        *(uv2*)(outp + ((size_t)r * 136 + c) * 4) = pk;
    }
    __syncthreads();
    if (tid < 4) {
        int f = tid;
        int r1 = r0 + 17;
        for (int k = 0; k < O - 1; ++k) {
            int a = prm[f][6 + k] + 3, bb = prm[f][15 + k] + 3;
            #pragma unroll
            for (int dy = -1; dy <= 1; ++dy) {
                int rr = bb + dy;
                if (rr >= r0 && rr < r1) {
                    ushort_t* rowp = outp + ((size_t)rr * 136 + a - 1) * 4 + f;
                    rowp[0] = 0x3F00u; rowp[4] = 0x3F00u; rowp[8] = 0x3F00u;
                }
            }
            if (bb >= r0 && bb < r1) outp[((size_t)bb * 136 + a) * 4 + f] = 0x3F80u;
        }
    }
}

// ---------------- prep_w1 ----------------
__global__ __launch_bounds__(256) void prep_w1_k(const float* __restrict__ w1,
                                                 ushort_t* __restrict__ w1p) {
    int idx = blockIdx.x * 256 + threadIdx.x;
    if (idx >= (int)W1P_ELEMS) return;
    int k = idx & 31, lr = (idx >> 5) & 15, slot = (idx >> 9) & 3, ky = idx >> 11;
    int hl = slot & 1, m = slot >> 1;
    int kx = k >> 2, ic = k & 3;
    int oc = m * 16 + lr;
    float w = (kx < 7) ? w1[((oc * 4 + ic) * 7 + ky) * 7 + kx] : 0.f;
    ushort_t h = f2bf_rne(w);
    w1p[idx] = hl ? f2bf_rne(w - bf2f(h)) : h;
}

// ---------------- conv1 MFMA: +bias+relu -> c1p packed bf16 h|l, [b][y][x][oc] ----------------
__global__ __launch_bounds__(256) void conv1_mfma_k(const ushort_t* __restrict__ tb,
                                                    const ushort_t* __restrict__ w1p,
                                                    const float* __restrict__ b1,
                                                    unsigned* __restrict__ c1p) {
    int b_l = blockIdx.x;
    int oyt = blockIdx.y;
    int wave = threadIdx.x >> 6, lane = threadIdx.x & 63;
    int lr = lane & 15, lq = lane >> 4;
    const ushort_t* tbb = tb + (size_t)b_l * 136 * 136 * 4;
    int aoff = lr * 32 + lq * 8;
    float bias[2][4];
    #pragma unroll
    for (int m = 0; m < 2; ++m)
        #pragma unroll
        for (int j = 0; j < 4; ++j)
            bias[m][j] = b1[m * 16 + lq * 4 + j];
    int oybase = oyt * 16 + wave * 4;
    #pragma unroll 1
    for (int yy = 0; yy < 4; ++yy) {
        int oy = oybase + yy;
        f32x4 acc[2][4];
        #pragma unroll
        for (int m = 0; m < 2; ++m)
            #pragma unroll
            for (int xt = 0; xt < 4; ++xt)
                acc[m][xt] = (f32x4)0.f;
        #pragma unroll
        for (int ky = 0; ky < 7; ++ky) {
            const ushort_t* wb = w1p + (size_t)ky * 2048;
            uv4 ah0 = *(const uv4*)(wb + aoff);
            uv4 al0 = *(const uv4*)(wb + 512 + aoff);
            uv4 ah1 = *(const uv4*)(wb + 1024 + aoff);
            uv4 al1 = *(const uv4*)(wb + 1536 + aoff);
            const ushort_t* rb = tbb + (size_t)(2 * oy + ky) * (136 * 4);
            #pragma unroll
            for (int xt = 0; xt < 4; ++xt) {
                uv4 bv = *(const uv4*)(rb + (size_t)(2 * (xt * 16 + lr) + 2 * lq) * 4);
                MFMA16(acc[0][xt], ah0, bv);
                MFMA16(acc[1][xt], ah1, bv);
                MFMA16(acc[0][xt], al0, bv);
                MFMA16(acc[1][xt], al1, bv);
            }
        }
        asm volatile("s_nop 7\n\ts_nop 7");
        #pragma unroll
        for (int m = 0; m < 2; ++m)
            #pragma unroll
            for (int xt = 0; xt < 4; ++xt) {
                uv4 pk;
                #pragma unroll
                for (int j = 0; j < 4; ++j) {
                    float v = fmaxf(acc[m][xt][j] + bias[m][j], 0.f);
                    ushort_t h = f2bf_rne(v);
                    ushort_t l = f2bf_rne(v - bf2f(h));
                    pk[j] = (unsigned)h | ((unsigned)l << 16);
                }
                *(uv4*)(c1p + (((size_t)b_l * 64 + oy) * 64 + xt * 16 + lr) * 32 + m * 16 + lq * 4) = pk;
            }
    }
}

// ---------------- pool1b: 3x3 s2 pool on packed c1p -> p1h/p1l padded [b][35][35][32] ----------------
__global__ __launch_bounds__(256) void pool1b_k(const unsigned* __restrict__ c1p,
                                                ushort_t* __restrict__ p1h,
                                                ushort_t* __restrict__ p1l, int n) {
    int idx = blockIdx.x * 256 + threadIdx.x;
    if (idx >= n) return;
    int ic = idx & 31; int t = idx >> 5;
    int pc = t % 35; t /= 35;
    int pr = t % 35; int b = t / 35;
    int py = pr - 2, px = pc - 2;
    float v = 0.f;
    if (py >= 0 && py < 31 && px >= 0 && px < 31) {
        const unsigned* base = c1p + (((size_t)b * 64 + 2 * py) * 64 + 2 * px) * 32 + ic;
        #pragma unroll
        for (int r = 0; r < 3; ++r)
            #pragma unroll
            for (int c = 0; c < 3; ++c) {
                unsigned u = base[(r * 64 + c) * 32];
                float f = bf2f((ushort_t)(u & 0xFFFFu)) + bf2f((ushort_t)(u >> 16));
                v = fmaxf(v, f);
            }
    }
    ushort_t h = f2bf_rne(v);
    p1h[idx] = h;
    p1l[idx] = f2bf_rne(v - bf2f(h));
}

// ---------------- prep_w2 ----------------
__global__ __launch_bounds__(256) void prep_w2_k(const float* __restrict__ w2,
                                                 ushort_t* __restrict__ w2p) {
    int idx = blockIdx.x * 256 + threadIdx.x;
    if (idx >= 25 * 64 * 32) return;
    int ic = idx & 31, oc = (idx >> 5) & 63, kk = idx >> 11;
    float w = w2[(size_t)(oc * 32 + ic) * 25 + kk];
    ushort_t h = f2bf_rne(w);
    w2p[(size_t)kk * 4096 + (idx & 2047)] = h;
    w2p[(size_t)kk * 4096 + 2048 + (idx & 2047)] = f2bf_rne(w - bf2f(h));
}

// ---------------- zero ----------------
__global__ __launch_bounds__(256) void zero_k(unsigned* __restrict__ p, int n) {
    int i = blockIdx.x * 256 + threadIdx.x;
    if (i < n) p[i] = 0u;
}

// ---------------- conv2 MFMA + LDS-staged B + fused bias/relu/pool2 ----------------
__global__ __launch_bounds__(256) void conv2_mfma_k(const ushort_t* __restrict__ p1h,
                                                    const ushort_t* __restrict__ p1l,
                                                    const ushort_t* __restrict__ w2p,
                                                    const float* __restrict__ b2,
                                                    ushort_t* __restrict__ p2h,
                                                    ushort_t* __restrict__ p2l) {
    __shared__ ushort_t sB[2][13440];   // [plane][r<12][pc<35][k<32], swizzled k-chunk; 53,760 B
    int b_l = blockIdx.x;
    int yt  = blockIdx.y;
    int y0 = yt * 8;
    int nrows = (35 - y0) < 12 ? (35 - y0) : 12;   // 12,12,12,11
    int tid = threadIdx.x;

    // stage: 16B chunks; chunk -> (plane, r, pc, lqi); swizzle k-chunk by ((pc>>1)&3)
    {
        int nchunks = nrows * 35 * 4;
        const ushort_t* src0 = p1h + (size_t)b_l * 35 * 1120 + (size_t)y0 * 1120;
        const ushort_t* src1 = p1l + (size_t)b_l * 35 * 1120 + (size_t)y0 * 1120;
        for (int c = tid; c < 2 * nchunks; c += 256) {
            int p = c >= nchunks;
            int cc = p ? c - nchunks : c;
            int lqi = cc & 3;
            int pc = (cc >> 2) % 35;
            int r = cc / 140;
            const ushort_t* s = p ? src1 : src0;
            uv4 v = *(const uv4*)(s + (size_t)r * 1120 + pc * 32 + lqi * 8);
            int swz = lqi ^ ((pc >> 1) & 3);
            *(uv4*)(&sB[p][(r * 35 + pc) * 32 + swz * 8]) = v;
        }
    }
    __syncthreads();

    int wave = threadIdx.x >> 6;
    int lane = threadIdx.x & 63;
    int wm = wave & 1, wy = wave >> 1;
    int oc0 = wm * 32;
    int lr = lane & 15, lq = lane >> 4;
    int rclip = 34 - y0;           // >= 11 for yt<3, ==10 for yt==3

    f32x4 acc[4][2][2];
    #pragma unroll
    for (int y = 0; y < 4; ++y)
        #pragma unroll
        for (int m = 0; m < 2; ++m)
            #pragma unroll
            for (int n = 0; n < 2; ++n)
                acc[y][m][n] = (f32x4)0.f;

    int aoff = (oc0 + lr) * 32 + lq * 8;

    #pragma unroll 1
    for (int kk = 0; kk < 25; ++kk) {
        int ky = kk / 5, kx = kk % 5;
        const ushort_t* wb = w2p + (size_t)kk * 4096;
        uv4 ah0 = *(const uv4*)(wb + aoff);
        uv4 ah1 = *(const uv4*)(wb + aoff + 512);
        uv4 al0 = *(const uv4*)(wb + 2048 + aoff);
        uv4 al1 = *(const uv4*)(wb + 2048 + aoff + 512);
        // per-xt column byte-index (elements) incl. swizzle
        int pcc[2];
        #pragma unroll
        for (int xt = 0; xt < 2; ++xt) {
            int pc = xt * 16 + lr + kx; pc = pc > 34 ? 34 : pc;
            pcc[xt] = pc * 32 + (lq ^ ((pc >> 1) & 3)) * 8;
        }
        #pragma unroll
        for (int y = 0; y < 4; ++y) {
            int r = wy * 4 + y + ky; r = r > rclip ? rclip : r;
            int rbase = r * 1120;   // r*35*32
            #pragma unroll
            for (int xt = 0; xt < 2; ++xt) {
                int off = rbase + pcc[xt];
                uv4 bh = *(const uv4*)(&sB[0][off]);
                uv4 bl = *(const uv4*)(&sB[1][off]);
                MFMA16(acc[y][0][xt], ah0, bh);
                MFMA16(acc[y][1][xt], ah1, bh);
                MFMA16(acc[y][0][xt], ah0, bl);
                MFMA16(acc[y][1][xt], ah1, bl);
                MFMA16(acc[y][0][xt], al0, bh);
                MFMA16(acc[y][1][xt], al1, bh);
            }
        }
    }
    asm volatile("s_nop 7\n\ts_nop 7");

    float bias[2][4];
    #pragma unroll
    for (int m = 0; m < 2; ++m)
        #pragma unroll
        for (int j = 0; j < 4; ++j)
            bias[m][j] = b2[oc0 + m * 16 + lq * 4 + j];

    int ybase = y0 + wy * 4;
    #pragma unroll
    for (int yp = 0; yp < 2; ++yp) {
        int yy = ybase + 2 * yp;
        if (yy + 1 > 30) continue;   // wave-uniform
        int py = yy >> 1;
        #pragma unroll
        for (int m = 0; m < 2; ++m)
            #pragma unroll
            for (int xt = 0; xt < 2; ++xt)
                #pragma unroll
                for (int j = 0; j < 4; ++j) {
                    float v = fmaxf(acc[2 * yp][m][xt][j], acc[2 * yp + 1][m][xt][j]);
                    float o = __shfl_xor(v, 1, 64);
                    v = fmaxf(fmaxf(v, o) + bias[m][j], 0.f);
                    int px = xt * 8 + (lr >> 1);
                    if (!(lane & 1) && px < 15) {
                        int oc = oc0 + m * 16 + lq * 4 + j;
                        size_t oo = (((size_t)b_l * 17 + py + 1) * 18 + px + 1) * 64 + oc;
                        ushort_t h = f2bf_rne(v);
                        p2h[oo] = h;
                        p2l[oo] = f2bf_rne(v - bf2f(h));
                    }
                }
    }
}

// ---------------- prep_w3 ----------------
__global__ __launch_bounds__(256) void prep_w3_k(const float* __restrict__ w3,
                                                 ushort_t* __restrict__ w3p) {
    int idx = blockIdx.x * 256 + threadIdx.x;
    if (idx >= (int)W3P_ELEMS) return;
    int kk = idx & 31, oc = (idx >> 5) & 127, hl = (idx >> 12) & 1, ks = (idx >> 13) & 1, kxy = idx >> 14;
    int ky = kxy / 3, kx = kxy % 3;
    int ic = ks * 32 + kk;
    float w = w3[((size_t)(oc * 64 + ic) * 3 + ky) * 3 + kx];
    ushort_t h = f2bf_rne(w);
    w3p[idx] = hl ? f2bf_rne(w - bf2f(h)) : h;
}

// ---------------- conv3 MFMA ----------------
__global__ __launch_bounds__(256) void conv3_mfma_k(const ushort_t* __restrict__ p2h,
                                                    const ushort_t* __restrict__ p2l,
                                                    const ushort_t* __restrict__ w3p,
                                                    const float* __restrict__ b3,
                                                    float* __restrict__ c3) {
    int b_l = blockIdx.x;
    int oy0 = blockIdx.y * 5;
    int wave = threadIdx.x >> 6, lane = threadIdx.x & 63;
    int lr = lane & 15, lq = lane >> 4;
    int oc0 = wave * 32;
    const ushort_t* ph = p2h + (size_t)b_l * 17 * 18 * 64;
    const ushort_t* pl = p2l + (size_t)b_l * 17 * 18 * 64;
    f32x4 acc[5][2];
    #pragma unroll
    for (int y = 0; y < 5; ++y) { acc[y][0] = (f32x4)0.f; acc[y][1] = (f32x4)0.f; }

    #pragma unroll 1
    for (int ky = 0; ky < 3; ++ky)
        #pragma unroll 1
        for (int kx = 0; kx < 3; ++kx)
            #pragma unroll
            for (int ks = 0; ks < 2; ++ks) {
                const ushort_t* wb = w3p + (size_t)(((ky * 3 + kx) * 2 + ks) * 2) * 4096;
                uv4 ah0 = *(const uv4*)(wb + (oc0 + lr) * 32 + lq * 8);
                uv4 ah1 = *(const uv4*)(wb + (oc0 + 16 + lr) * 32 + lq * 8);
                uv4 al0 = *(const uv4*)(wb + 4096 + (oc0 + lr) * 32 + lq * 8);
                uv4 al1 = *(const uv4*)(wb + 4096 + (oc0 + 16 + lr) * 32 + lq * 8);
                #pragma unroll
                for (int yy = 0; yy < 5; ++yy) {
                    size_t off = ((size_t)(oy0 + yy + ky) * 18 + lr + kx) * 64 + ks * 32 + lq * 8;
                    uv4 bh = *(const uv4*)(ph + off);
                    uv4 bl = *(const uv4*)(pl + off);
                    MFMA16(acc[yy][0], ah0, bh);
                    MFMA16(acc[yy][1], ah1, bh);
                    MFMA16(acc[yy][0], ah0, bl);
                    MFMA16(acc[yy][1], ah1, bl);
                    MFMA16(acc[yy][0], al0, bh);
                    MFMA16(acc[yy][1], al1, bh);
                }
            }
    asm volatile("s_nop 7\n\ts_nop 7");
    if (lr < 15) {
        #pragma unroll
        for (int yy = 0; yy < 5; ++yy)
            #pragma unroll
            for (int m = 0; m < 2; ++m)
                #pragma unroll
                for (int j = 0; j < 4; ++j) {
                    int oc = oc0 + m * 16 + lq * 4 + j;
                    float v = fmaxf(acc[yy][m][j] + b3[oc], 0.f);
                    c3[((size_t)b_l * 128 + oc) * 225 + (oy0 + yy) * 15 + lr] = v;
                }
    }
}

// ---------------- pool3 + mean ----------------
__global__ __launch_bounds__(256) void pool3mean_k(const float* __restrict__ c3,
                                                   float* __restrict__ feat, int b0, int n) {
    int idx = blockIdx.x * 256 + threadIdx.x;
    if (idx >= n) return;
    int oc = idx & 127, b_l = idx >> 7;
    const float* base = c3 + (size_t)idx * 225;
    float s = 0.f;
    #pragma unroll
    for (int py = 0; py < 7; ++py)
        #pragma unroll
        for (int px = 0; px < 7; ++px) {
            float m = fmaxf(fmaxf(base[(2 * py) * 15 + 2 * px],     base[(2 * py) * 15 + 2 * px + 1]),
                            fmaxf(base[(2 * py + 1) * 15 + 2 * px], base[(2 * py + 1) * 15 + 2 * px + 1]));
            s += m;
        }
    feat[(size_t)(b0 + b_l) * 128 + oc] = s * (1.f / 49.f);
}

// ---------------- fc1 (relu) + fc2 ----------------
__global__ __launch_bounds__(128) void fc_k(const float* __restrict__ feat,
                                            const float* __restrict__ fw1,
                                            const float* __restrict__ fb1,
                                            const float* __restrict__ fw2,
                                            const float* __restrict__ fb2,
                                            float* __restrict__ out) {
    __shared__ float sF[128];
    __shared__ float sH[128];
    int b = blockIdx.x, tid = threadIdx.x;
    sF[tid] = feat[(size_t)b * 128 + tid];
    __syncthreads();
    const float4* wrow = (const float4*)(fw1 + (size_t)tid * 128);
    float s = fb1[tid];
    #pragma unroll
    for (int i = 0; i < 32; ++i) {
        float4 w = wrow[i];
        s = fmaf(w.x, sF[4 * i], s);
        s = fmaf(w.y, sF[4 * i + 1], s);
        s = fmaf(w.z, sF[4 * i + 2], s);
        s = fmaf(w.w, sF[4 * i + 3], s);
    }
    sH[tid] = fmaxf(s, 0.f);
    __syncthreads();
    if (tid < 5) {
        const float* w2r = fw2 + (size_t)tid * 128;
        float s2 = fb2[tid];
        for (int i = 0; i < 128; ++i) s2 = fmaf(w2r[i], sH[i], s2);
        out[(size_t)b * 5 + tid] = s2;
    }
}

// ---------------- launch ----------------
extern "C" void kernel_launch(void* const* d_in, const int* in_sizes, int n_in,
                              void* d_out, int out_size, void* d_ws, size_t ws_size,
                              hipStream_t stream) {
    const int*   x   = (const int*)d_in[0];
    const float* w1  = (const float*)d_in[1];
    const float* b1  = (const float*)d_in[2];
    const float* w2  = (const float*)d_in[3];
    const float* b2  = (const float*)d_in[4];
    const float* w3  = (const float*)d_in[5];
    const float* b3  = (const float*)d_in[6];
    const float* fw1 = (const float*)d_in[7];
    const float* fb1 = (const float*)d_in[8];
    const float* fw2 = (const float*)d_in[9];
    const float* fb2 = (const float*)d_in[10];
    float* out = (float*)d_out;

    // choose per-dispatch batch NB by available workspace (prefer full batch)
    const size_t per_img = C1_B + C3_B + TB_B + 2 * P1_B + 2 * P2_B;
    const size_t fixed_b = FEAT_B + (W1P_ELEMS + W2P_ELEMS + W3P_ELEMS) * 2 + 1024;
    int NB = Bfull;
    while (NB > 128 && fixed_b + per_img * (size_t)NB > ws_size) NB >>= 1;

    char* base = (char*)d_ws;
    unsigned* c1p = (unsigned*)base;                    base += (size_t)NB * C1_B;
    float* c3_c = (float*)base;                         base += (size_t)NB * C3_B;
    float* feat = (float*)base;                         base += FEAT_B;
    ushort_t* tb  = (ushort_t*)base;                    base += (size_t)NB * TB_B;
    ushort_t* p1h = (ushort_t*)base;                    base += (size_t)NB * P1_B;
    ushort_t* p1l = (ushort_t*)base;                    base += (size_t)NB * P1_B;
    ushort_t* p2h = (ushort_t*)base;                    base += (size_t)NB * P2_B;
    ushort_t* p2l = (ushort_t*)base;                    base += (size_t)NB * P2_B;
    ushort_t* w1p = (ushort_t*)base;                    base += W1P_ELEMS * 2;
    ushort_t* w2p = (ushort_t*)base;                    base += W2P_ELEMS * 2;
    ushort_t* w3p = (ushort_t*)base;

    prep_w1_k<<<((int)W1P_ELEMS + 255) / 256, 256, 0, stream>>>(w1, w1p);
    prep_w2_k<<<(25 * 64 * 32 + 255) / 256, 256, 0, stream>>>(w2, w2p);
    prep_w3_k<<<((int)W3P_ELEMS + 255) / 256, 256, 0, stream>>>(w3, w3p);

    const int nchunk = Bfull / NB;
    const int p2_uints = NB * (17 * 18 * 64 * 2 / 2);   // h+l planes as uints
    const int p1_n = NB * 35 * 35 * 32;
    for (int ch = 0; ch < nchunk; ++ch) {
        int b0 = ch * NB;
        rasterize_bf_k<<<dim3(NB, 8), 256, 0, stream>>>(x, tb, b0);
        conv1_mfma_k<<<dim3(NB, 4), 256, 0, stream>>>(tb, w1p, b1, c1p);
        pool1b_k<<<(p1_n + 255) / 256, 256, 0, stream>>>(c1p, p1h, p1l, p1_n);
        zero_k<<<(p2_uints + 255) / 256, 256, 0, stream>>>((unsigned*)p2h, p2_uints);
        conv2_mfma_k<<<dim3(NB, 4), 256, 0, stream>>>(p1h, p1l, w2p, b2, p2h, p2l);
        conv3_mfma_k<<<dim3(NB, 3), 256, 0, stream>>>(p2h, p2l, w3p, b3, c3_c);
        pool3mean_k<<<(NB * 128 + 255) / 256, 256, 0, stream>>>(c3_c, feat, b0, NB * 128);
    }
    fc_k<<<Bfull, 128, 0, stream>>>(feat, fw1, fb1, fw2, fb2, out);
}

// Round 9
// 481.121 us; speedup vs baseline: 4.2312x; 1.2447x over previous
//
#include <hip/hip_runtime.h>
#include <cstddef>

typedef unsigned short ushort_t;
typedef unsigned uv4 __attribute__((ext_vector_type(4)));
typedef unsigned uv2 __attribute__((ext_vector_type(2)));
typedef float f32x4 __attribute__((ext_vector_type(4)));

// ---------------- problem constants ----------------
constexpr int Bfull = 512;
constexpr int F = 4, O = 10;

// per-image byte sizes (all 16B-aligned)
constexpr size_t TB_B  = (size_t)136 * 136 * 4 * 2;   // 147,968
constexpr size_t C1_B  = (size_t)64 * 64 * 32 * 4;    // 524,288 (uint h|l<<16, [y][x][oc])
constexpr size_t P1_B  = (size_t)35 * 35 * 32 * 2;    // 78,400 (each of h,l)
constexpr size_t P2_B  = (size_t)17 * 18 * 64 * 2;    // 39,168 (each of h,l)
constexpr size_t FEAT_B = (size_t)Bfull * 128 * 4;    // 262,144
constexpr size_t W1P_ELEMS = (size_t)7 * 4 * 16 * 32;        // 28672 ushort
constexpr size_t W2P_ELEMS = (size_t)25 * 2 * 64 * 32;       // 102400 ushort
constexpr size_t W3P_ELEMS = (size_t)9 * 2 * 2 * 128 * 32;   // 147456 ushort

__device__ __forceinline__ ushort_t f2bf_rne(float x) {
    unsigned u = __builtin_bit_cast(unsigned, x);
    unsigned r = (u + 0x7FFFu + ((u >> 16) & 1u)) >> 16;
    return (ushort_t)r;
}
__device__ __forceinline__ float bf2f(ushort_t b) {
    return __builtin_bit_cast(float, (unsigned)b << 16);
}

#define MFMA16(acc, a, b) \
    asm("v_mfma_f32_16x16x32_bf16 %0, %1, %2, %0" : "+v"(acc) : "v"(a), "v"(b))

// ---------------- rasterize -> padded bf16 [b][136r][136c][4ic] ----------------
__global__ __launch_bounds__(256) void rasterize_bf_k(const int* __restrict__ x,
                                                      ushort_t* __restrict__ tb, int b0) {
    int b_l = blockIdx.x;
    int rg  = blockIdx.y;             // row-group 0..7
    int b = b0 + b_l;
    __shared__ int pts[F][O][2];
    __shared__ int prm[F][24];
    int tid = threadIdx.x;
    if (tid < F * O * 2)
        ((int*)pts)[tid] = x[(size_t)b * F * O * 2 + tid];
    __syncthreads();
    if (tid < F) {
        int f = tid;
        int dX = 64 + pts[f][O - 1][0];
        int dY = 64 - pts[f][O - 1][1];
        prm[f][0] = dX; prm[f][1] = dY;
        prm[f][2] = dX >= 64 ? 64 : dX + 1; prm[f][3] = dX >= 64 ? dX - 1 : 64;
        prm[f][4] = dY >= 64 ? 64 : dY + 1; prm[f][5] = dY >= 64 ? dY - 1 : 64;
        for (int k = 0; k < O - 1; ++k) {
            prm[f][6 + k]  = (pts[f][k][0] + 64) % 127;
            prm[f][15 + k] = (64 - pts[f][k][1]) % 127;
        }
    }
    __syncthreads();
    ushort_t* outp = tb + (size_t)b_l * 136 * 136 * 4;
    int r0 = rg * 17;
    for (int i = tid; i < 17 * 136; i += 256) {
        int r = r0 + i / 136, c = i % 136;
        int y = r - 3, xx = c - 3;
        unsigned pack0 = 0, pack1 = 0;
        if (y >= 0 && y < 128 && xx >= 0 && xx < 128) {
            bool ctr9 = (y >= 63 && y <= 65 && xx >= 63 && xx <= 65);
            bool ctr1 = (y == 64 && xx == 64);
            #pragma unroll
            for (int f = 0; f < 4; ++f) {
                unsigned bf;
                if (ctr1) bf = 0x3F80u;
                else if (ctr9) bf = 0x3F00u;
                else {
                    int dX = prm[f][0];
                    bool mX = (xx >= prm[f][2]) && (xx <= prm[f][3]);
                    bool mY = (y >= prm[f][4]) && (y <= prm[f][5]);
                    bf = ((mX && y == 64) || (mY && xx == dX)) ? 0xBF80u : 0u;
                }
                if (f & 1) { if (f >> 1) pack1 |= bf << 16; else pack0 |= bf << 16; }
                else       { if (f >> 1) pack1 |= bf;       else pack0 |= bf; }
            }
        }
        uv2 pk; pk.x = pack0; pk.y = pack1;
        *(uv2*)(outp + ((size_t)r * 136 + c) * 4) = pk;
    }
    __syncthreads();
    if (tid < 4) {
        int f = tid;
        int r1 = r0 + 17;
        for (int k = 0; k < O - 1; ++k) {
            int a = prm[f][6 + k] + 3, bb = prm[f][15 + k] + 3;
            #pragma unroll
            for (int dy = -1; dy <= 1; ++dy) {
                int rr = bb + dy;
                if (rr >= r0 && rr < r1) {
                    ushort_t* rowp = outp + ((size_t)rr * 136 + a - 1) * 4 + f;
                    rowp[0] = 0x3F00u; rowp[4] = 0x3F00u; rowp[8] = 0x3F00u;
                }
            }
            if (bb >= r0 && bb < r1) outp[((size_t)bb * 136 + a) * 4 + f] = 0x3F80u;
        }
    }
}

// ---------------- prep_w1 ----------------
__global__ __launch_bounds__(256) void prep_w1_k(const float* __restrict__ w1,
                                                 ushort_t* __restrict__ w1p) {
    int idx = blockIdx.x * 256 + threadIdx.x;
    if (idx >= (int)W1P_ELEMS) return;
    int k = idx & 31, lr = (idx >> 5) & 15, slot = (idx >> 9) & 3, ky = idx >> 11;
    int hl = slot & 1, m = slot >> 1;
    int kx = k >> 2, ic = k & 3;
    int oc = m * 16 + lr;
    float w = (kx < 7) ? w1[((oc * 4 + ic) * 7 + ky) * 7 + kx] : 0.f;
    ushort_t h = f2bf_rne(w);
    w1p[idx] = hl ? f2bf_rne(w - bf2f(h)) : h;
}

// ---------------- conv1 MFMA: +bias+relu -> c1p packed bf16 h|l, [b][y][x][oc] ----------------
__global__ __launch_bounds__(256) void conv1_mfma_k(const ushort_t* __restrict__ tb,
                                                    const ushort_t* __restrict__ w1p,
                                                    const float* __restrict__ b1,
                                                    unsigned* __restrict__ c1p) {
    int b_l = blockIdx.x;
    int oyt = blockIdx.y;
    int wave = threadIdx.x >> 6, lane = threadIdx.x & 63;
    int lr = lane & 15, lq = lane >> 4;
    const ushort_t* tbb = tb + (size_t)b_l * 136 * 136 * 4;
    int aoff = lr * 32 + lq * 8;
    float bias[2][4];
    #pragma unroll
    for (int m = 0; m < 2; ++m)
        #pragma unroll
        for (int j = 0; j < 4; ++j)
            bias[m][j] = b1[m * 16 + lq * 4 + j];
    int oybase = oyt * 16 + wave * 4;
    #pragma unroll 1
    for (int yy = 0; yy < 4; ++yy) {
        int oy = oybase + yy;
        f32x4 acc[2][4];
        #pragma unroll
        for (int m = 0; m < 2; ++m)
            #pragma unroll
            for (int xt = 0; xt < 4; ++xt)
                acc[m][xt] = (f32x4)0.f;
        #pragma unroll
        for (int ky = 0; ky < 7; ++ky) {
            const ushort_t* wb = w1p + (size_t)ky * 2048;
            uv4 ah0 = *(const uv4*)(wb + aoff);
            uv4 al0 = *(const uv4*)(wb + 512 + aoff);
            uv4 ah1 = *(const uv4*)(wb + 1024 + aoff);
            uv4 al1 = *(const uv4*)(wb + 1536 + aoff);
            const ushort_t* rb = tbb + (size_t)(2 * oy + ky) * (136 * 4);
            #pragma unroll
            for (int xt = 0; xt < 4; ++xt) {
                uv4 bv = *(const uv4*)(rb + (size_t)(2 * (xt * 16 + lr) + 2 * lq) * 4);
                MFMA16(acc[0][xt], ah0, bv);
                MFMA16(acc[1][xt], ah1, bv);
                MFMA16(acc[0][xt], al0, bv);
                MFMA16(acc[1][xt], al1, bv);
            }
        }
        asm volatile("s_nop 7\n\ts_nop 7");
        #pragma unroll
        for (int m = 0; m < 2; ++m)
            #pragma unroll
            for (int xt = 0; xt < 4; ++xt) {
                uv4 pk;
                #pragma unroll
                for (int j = 0; j < 4; ++j) {
                    float v = fmaxf(acc[m][xt][j] + bias[m][j], 0.f);
                    ushort_t h = f2bf_rne(v);
                    ushort_t l = f2bf_rne(v - bf2f(h));
                    pk[j] = (unsigned)h | ((unsigned)l << 16);
                }
                *(uv4*)(c1p + (((size_t)b_l * 64 + oy) * 64 + xt * 16 + lr) * 32 + m * 16 + lq * 4) = pk;
            }
    }
}

// ---------------- pool1b: 3x3 s2 pool on packed c1p -> p1h/p1l padded [b][35][35][32] ----------------
__global__ __launch_bounds__(256) void pool1b_k(const unsigned* __restrict__ c1p,
                                                ushort_t* __restrict__ p1h,
                                                ushort_t* __restrict__ p1l, int n) {
    int idx = blockIdx.x * 256 + threadIdx.x;
    if (idx >= n) return;
    int ic = idx & 31; int t = idx >> 5;
    int pc = t % 35; t /= 35;
    int pr = t % 35; int b = t / 35;
    int py = pr - 2, px = pc - 2;
    float v = 0.f;
    if (py >= 0 && py < 31 && px >= 0 && px < 31) {
        const unsigned* base = c1p + (((size_t)b * 64 + 2 * py) * 64 + 2 * px) * 32 + ic;
        #pragma unroll
        for (int r = 0; r < 3; ++r)
            #pragma unroll
            for (int c = 0; c < 3; ++c) {
                unsigned u = base[(r * 64 + c) * 32];
                float f = bf2f((ushort_t)(u & 0xFFFFu)) + bf2f((ushort_t)(u >> 16));
                v = fmaxf(v, f);
            }
    }
    ushort_t h = f2bf_rne(v);
    p1h[idx] = h;
    p1l[idx] = f2bf_rne(v - bf2f(h));
}

// ---------------- prep_w2 ----------------
__global__ __launch_bounds__(256) void prep_w2_k(const float* __restrict__ w2,
                                                 ushort_t* __restrict__ w2p) {
    int idx = blockIdx.x * 256 + threadIdx.x;
    if (idx >= 25 * 64 * 32) return;
    int ic = idx & 31, oc = (idx >> 5) & 63, kk = idx >> 11;
    float w = w2[(size_t)(oc * 32 + ic) * 25 + kk];
    ushort_t h = f2bf_rne(w);
    w2p[(size_t)kk * 4096 + (idx & 2047)] = h;
    w2p[(size_t)kk * 4096 + 2048 + (idx & 2047)] = f2bf_rne(w - bf2f(h));
}

// ---------------- zero only the p2 padding cells ----------------
// pad cells of [17][18]: r==0 (18), r==16 (18), r=1..15 x c in {0,16,17} (45) -> 81 cells
__global__ __launch_bounds__(256) void zero_pad_k(ushort_t* __restrict__ p2h,
                                                  ushort_t* __restrict__ p2l, int n) {
    int idx = blockIdx.x * 256 + threadIdx.x;
    if (idx >= n) return;
    int ic = idx & 63; int t = idx >> 6;
    int cell = t % 81; int t2 = t / 81;
    int pl = t2 & 1; int b = t2 >> 1;
    int r, c;
    if (cell < 18) { r = 0; c = cell; }
    else if (cell < 36) { r = 16; c = cell - 18; }
    else { int q = cell - 36; r = 1 + q / 3; int m = q % 3; c = (m == 0) ? 0 : 15 + m; }
    size_t off = (((size_t)b * 17 + r) * 18 + c) * 64 + ic;
    (pl ? p2l : p2h)[off] = 0;
}

// ---------------- conv2 MFMA + LDS-staged B + fused bias/relu/pool2 ----------------
__global__ __launch_bounds__(256) void conv2_mfma_k(const ushort_t* __restrict__ p1h,
                                                    const ushort_t* __restrict__ p1l,
                                                    const ushort_t* __restrict__ w2p,
                                                    const float* __restrict__ b2,
                                                    ushort_t* __restrict__ p2h,
                                                    ushort_t* __restrict__ p2l) {
    __shared__ ushort_t sB[2][13440];   // [plane][r<12][pc<35][k<32], swizzled k-chunk
    int b_l = blockIdx.x;
    int yt  = blockIdx.y;
    int y0 = yt * 8;
    int nrows = (35 - y0) < 12 ? (35 - y0) : 12;   // 12,12,12,11
    int tid = threadIdx.x;

    {
        int nchunks = nrows * 35 * 4;
        const ushort_t* src0 = p1h + (size_t)b_l * 35 * 1120 + (size_t)y0 * 1120;
        const ushort_t* src1 = p1l + (size_t)b_l * 35 * 1120 + (size_t)y0 * 1120;
        for (int c = tid; c < 2 * nchunks; c += 256) {
            int p = c >= nchunks;
            int cc = p ? c - nchunks : c;
            int lqi = cc & 3;
            int pc = (cc >> 2) % 35;
            int r = cc / 140;
            const ushort_t* s = p ? src1 : src0;
            uv4 v = *(const uv4*)(s + (size_t)r * 1120 + pc * 32 + lqi * 8);
            int swz = lqi ^ ((pc >> 1) & 3);
            *(uv4*)(&sB[p][(r * 35 + pc) * 32 + swz * 8]) = v;
        }
    }
    __syncthreads();

    int wave = threadIdx.x >> 6;
    int lane = threadIdx.x & 63;
    int wm = wave & 1, wy = wave >> 1;
    int oc0 = wm * 32;
    int lr = lane & 15, lq = lane >> 4;
    int rclip = 34 - y0;

    f32x4 acc[4][2][2];
    #pragma unroll
    for (int y = 0; y < 4; ++y)
        #pragma unroll
        for (int m = 0; m < 2; ++m)
            #pragma unroll
            for (int n = 0; n < 2; ++n)
                acc[y][m][n] = (f32x4)0.f;

    int aoff = (oc0 + lr) * 32 + lq * 8;

    #pragma unroll 1
    for (int kk = 0; kk < 25; ++kk) {
        int ky = kk / 5, kx = kk % 5;
        const ushort_t* wb = w2p + (size_t)kk * 4096;
        uv4 ah0 = *(const uv4*)(wb + aoff);
        uv4 ah1 = *(const uv4*)(wb + aoff + 512);
        uv4 al0 = *(const uv4*)(wb + 2048 + aoff);
        uv4 al1 = *(const uv4*)(wb + 2048 + aoff + 512);
        int pcc[2];
        #pragma unroll
        for (int xt = 0; xt < 2; ++xt) {
            int pc = xt * 16 + lr + kx; pc = pc > 34 ? 34 : pc;
            pcc[xt] = pc * 32 + (lq ^ ((pc >> 1) & 3)) * 8;
        }
        #pragma unroll
        for (int y = 0; y < 4; ++y) {
            int r = wy * 4 + y + ky; r = r > rclip ? rclip : r;
            int rbase = r * 1120;
            #pragma unroll
            for (int xt = 0; xt < 2; ++xt) {
                int off = rbase + pcc[xt];
                uv4 bh = *(const uv4*)(&sB[0][off]);
                uv4 bl = *(const uv4*)(&sB[1][off]);
                MFMA16(acc[y][0][xt], ah0, bh);
                MFMA16(acc[y][1][xt], ah1, bh);
                MFMA16(acc[y][0][xt], ah0, bl);
                MFMA16(acc[y][1][xt], ah1, bl);
                MFMA16(acc[y][0][xt], al0, bh);
                MFMA16(acc[y][1][xt], al1, bh);
            }
        }
    }
    asm volatile("s_nop 7\n\ts_nop 7");

    float bias[2][4];
    #pragma unroll
    for (int m = 0; m < 2; ++m)
        #pragma unroll
        for (int j = 0; j < 4; ++j)
            bias[m][j] = b2[oc0 + m * 16 + lq * 4 + j];

    int ybase = y0 + wy * 4;
    #pragma unroll
    for (int yp = 0; yp < 2; ++yp) {
        int yy = ybase + 2 * yp;
        if (yy + 1 > 30) continue;   // wave-uniform
        int py = yy >> 1;
        #pragma unroll
        for (int m = 0; m < 2; ++m)
            #pragma unroll
            for (int xt = 0; xt < 2; ++xt)
                #pragma unroll
                for (int j = 0; j < 4; ++j) {
                    float v = fmaxf(acc[2 * yp][m][xt][j], acc[2 * yp + 1][m][xt][j]);
                    float o = __shfl_xor(v, 1, 64);
                    v = fmaxf(fmaxf(v, o) + bias[m][j], 0.f);
                    int px = xt * 8 + (lr >> 1);
                    if (!(lane & 1) && px < 15) {
                        int oc = oc0 + m * 16 + lq * 4 + j;
                        size_t oo = (((size_t)b_l * 17 + py + 1) * 18 + px + 1) * 64 + oc;
                        ushort_t h = f2bf_rne(v);
                        p2h[oo] = h;
                        p2l[oo] = f2bf_rne(v - bf2f(h));
                    }
                }
    }
}

// ---------------- prep_w3 ----------------
__global__ __launch_bounds__(256) void prep_w3_k(const float* __restrict__ w3,
                                                 ushort_t* __restrict__ w3p) {
    int idx = blockIdx.x * 256 + threadIdx.x;
    if (idx >= (int)W3P_ELEMS) return;
    int kk = idx & 31, oc = (idx >> 5) & 127, hl = (idx >> 12) & 1, ks = (idx >> 13) & 1, kxy = idx >> 14;
    int ky = kxy / 3, kx = kxy % 3;
    int ic = ks * 32 + kk;
    float w = w3[((size_t)(oc * 64 + ic) * 3 + ky) * 3 + kx];
    ushort_t h = f2bf_rne(w);
    w3p[idx] = hl ? f2bf_rne(w - bf2f(h)) : h;
}

// ---------------- conv3 + pool3 + mean, fused -> feat ----------------
// grid (NB); block = 4 waves (oc groups of 32); full p2 image staged in LDS (swizzled).
// Output rows/cols 14 are never used by the 2x2 VALID pool -> skipped.
__global__ __launch_bounds__(256) void conv3pool_k(const ushort_t* __restrict__ p2h,
                                                   const ushort_t* __restrict__ p2l,
                                                   const ushort_t* __restrict__ w3p,
                                                   const float* __restrict__ b3,
                                                   float* __restrict__ feat, int b0) {
    __shared__ ushort_t sB[2][19584];   // [plane][rc<306][64], 16B slots swizzled by c&7
    int b_l = blockIdx.x;
    int tid = threadIdx.x;
    {
        const ushort_t* s0 = p2h + (size_t)b_l * 19584;
        const ushort_t* s1 = p2l + (size_t)b_l * 19584;
        for (int ccg = tid; ccg < 4896; ccg += 256) {
            int p = ccg >= 2448;
            int cc = p ? ccg - 2448 : ccg;
            int rc = cc >> 3, slot = cc & 7;
            int c = rc % 18;
            uv4 v = *(const uv4*)((p ? s1 : s0) + (size_t)cc * 8);
            *(uv4*)(&sB[p][rc * 64 + (slot ^ (c & 7)) * 8]) = v;
        }
    }
    __syncthreads();
    int wave = tid >> 6, lane = tid & 63;
    int lr = lane & 15, lq = lane >> 4;
    int oc0 = wave * 32;
    float bias[2][4];
    #pragma unroll
    for (int m = 0; m < 2; ++m)
        #pragma unroll
        for (int j = 0; j < 4; ++j)
            bias[m][j] = b3[oc0 + m * 16 + lq * 4 + j];
    f32x4 fsum[2];
    fsum[0] = (f32x4)0.f; fsum[1] = (f32x4)0.f;

    int cl = lr;   // output col = lr
    #pragma unroll 1
    for (int pr = 0; pr < 7; ++pr) {
        f32x4 acc[2][2];
        #pragma unroll
        for (int rr = 0; rr < 2; ++rr) { acc[rr][0] = (f32x4)0.f; acc[rr][1] = (f32x4)0.f; }
        #pragma unroll 1
        for (int ky = 0; ky < 3; ++ky)
            #pragma unroll 1
            for (int kx = 0; kx < 3; ++kx) {
                int c = cl + kx;
                int cs = c & 7;
                #pragma unroll
                for (int ks = 0; ks < 2; ++ks) {
                    const ushort_t* wb = w3p + (size_t)(((ky * 3 + kx) * 2 + ks) * 2) * 4096;
                    uv4 ah0 = *(const uv4*)(wb + (oc0 + lr) * 32 + lq * 8);
                    uv4 ah1 = *(const uv4*)(wb + (oc0 + 16 + lr) * 32 + lq * 8);
                    uv4 al0 = *(const uv4*)(wb + 4096 + (oc0 + lr) * 32 + lq * 8);
                    uv4 al1 = *(const uv4*)(wb + 4096 + (oc0 + 16 + lr) * 32 + lq * 8);
                    int slotk = ((ks << 2) | lq) ^ cs;
                    #pragma unroll
                    for (int rr = 0; rr < 2; ++rr) {
                        int r = 2 * pr + rr + ky;
                        int off = (r * 18 + c) * 64 + slotk * 8;
                        uv4 bh = *(const uv4*)(&sB[0][off]);
                        uv4 bl = *(const uv4*)(&sB[1][off]);
                        MFMA16(acc[rr][0], ah0, bh);
                        MFMA16(acc[rr][1], ah1, bh);
                        MFMA16(acc[rr][0], ah0, bl);
                        MFMA16(acc[rr][1], ah1, bl);
                        MFMA16(acc[rr][0], al0, bh);
                        MFMA16(acc[rr][1], al1, bh);
                    }
                }
            }
        asm volatile("s_nop 7\n\ts_nop 7");
        #pragma unroll
        for (int m = 0; m < 2; ++m)
            #pragma unroll
            for (int j = 0; j < 4; ++j) {
                float v0 = fmaxf(acc[0][m][j] + bias[m][j], 0.f);
                float v1 = fmaxf(acc[1][m][j] + bias[m][j], 0.f);
                float vm = fmaxf(v0, v1);
                float o = __shfl_xor(vm, 1, 64);
                float pooled = fmaxf(vm, o);
                if (lr < 14) fsum[m][j] += pooled;
            }
    }
    // reduce over cols (each px counted twice) and store mean
    #pragma unroll
    for (int m = 0; m < 2; ++m)
        #pragma unroll
        for (int j = 0; j < 4; ++j) {
            float t = fsum[m][j];
            t += __shfl_xor(t, 1, 64);
            t += __shfl_xor(t, 2, 64);
            t += __shfl_xor(t, 4, 64);
            t += __shfl_xor(t, 8, 64);
            if (lr == 0)
                feat[(size_t)(b0 + b_l) * 128 + oc0 + m * 16 + lq * 4 + j] = t * (1.f / 98.f);
        }
}

// ---------------- fc1 (relu) + fc2 ----------------
__global__ __launch_bounds__(128) void fc_k(const float* __restrict__ feat,
                                            const float* __restrict__ fw1,
                                            const float* __restrict__ fb1,
                                            const float* __restrict__ fw2,
                                            const float* __restrict__ fb2,
                                            float* __restrict__ out) {
    __shared__ float sF[128];
    __shared__ float sH[128];
    int b = blockIdx.x, tid = threadIdx.x;
    sF[tid] = feat[(size_t)b * 128 + tid];
    __syncthreads();
    const float4* wrow = (const float4*)(fw1 + (size_t)tid * 128);
    float s = fb1[tid];
    #pragma unroll
    for (int i = 0; i < 32; ++i) {
        float4 w = wrow[i];
        s = fmaf(w.x, sF[4 * i], s);
        s = fmaf(w.y, sF[4 * i + 1], s);
        s = fmaf(w.z, sF[4 * i + 2], s);
        s = fmaf(w.w, sF[4 * i + 3], s);
    }
    sH[tid] = fmaxf(s, 0.f);
    __syncthreads();
    if (tid < 5) {
        const float* w2r = fw2 + (size_t)tid * 128;
        float s2 = fb2[tid];
        for (int i = 0; i < 128; ++i) s2 = fmaf(w2r[i], sH[i], s2);
        out[(size_t)b * 5 + tid] = s2;
    }
}

// ---------------- launch ----------------
extern "C" void kernel_launch(void* const* d_in, const int* in_sizes, int n_in,
                              void* d_out, int out_size, void* d_ws, size_t ws_size,
                              hipStream_t stream) {
    const int*   x   = (const int*)d_in[0];
    const float* w1  = (const float*)d_in[1];
    const float* b1  = (const float*)d_in[2];
    const float* w2  = (const float*)d_in[3];
    const float* b2  = (const float*)d_in[4];
    const float* w3  = (const float*)d_in[5];
    const float* b3  = (const float*)d_in[6];
    const float* fw1 = (const float*)d_in[7];
    const float* fb1 = (const float*)d_in[8];
    const float* fw2 = (const float*)d_in[9];
    const float* fb2 = (const float*)d_in[10];
    float* out = (float*)d_out;

    const size_t per_img = C1_B + TB_B + 2 * P1_B + 2 * P2_B;   // 907,392 B
    const size_t fixed_b = FEAT_B + (W1P_ELEMS + W2P_ELEMS + W3P_ELEMS) * 2 + 1024;
    int NB = Bfull;
    while (NB > 128 && fixed_b + per_img * (size_t)NB > ws_size) NB >>= 1;

    char* base = (char*)d_ws;
    unsigned* c1p = (unsigned*)base;                    base += (size_t)NB * C1_B;
    float* feat = (float*)base;                         base += FEAT_B;
    ushort_t* tb  = (ushort_t*)base;                    base += (size_t)NB * TB_B;
    ushort_t* p1h = (ushort_t*)base;                    base += (size_t)NB * P1_B;
    ushort_t* p1l = (ushort_t*)base;                    base += (size_t)NB * P1_B;
    ushort_t* p2h = (ushort_t*)base;                    base += (size_t)NB * P2_B;
    ushort_t* p2l = (ushort_t*)base;                    base += (size_t)NB * P2_B;
    ushort_t* w1p = (ushort_t*)base;                    base += W1P_ELEMS * 2;
    ushort_t* w2p = (ushort_t*)base;                    base += W2P_ELEMS * 2;
    ushort_t* w3p = (ushort_t*)base;

    prep_w1_k<<<((int)W1P_ELEMS + 255) / 256, 256, 0, stream>>>(w1, w1p);
    prep_w2_k<<<(25 * 64 * 32 + 255) / 256, 256, 0, stream>>>(w2, w2p);
    prep_w3_k<<<((int)W3P_ELEMS + 255) / 256, 256, 0, stream>>>(w3, w3p);

    const int nchunk = Bfull / NB;
    const int pad_n = NB * 81 * 64 * 2;
    const int p1_n = NB * 35 * 35 * 32;
    for (int ch = 0; ch < nchunk; ++ch) {
        int b0 = ch * NB;
        rasterize_bf_k<<<dim3(NB, 8), 256, 0, stream>>>(x, tb, b0);
        conv1_mfma_k<<<dim3(NB, 4), 256, 0, stream>>>(tb, w1p, b1, c1p);
        pool1b_k<<<(p1_n + 255) / 256, 256, 0, stream>>>(c1p, p1h, p1l, p1_n);
        zero_pad_k<<<(pad_n + 255) / 256, 256, 0, stream>>>(p2h, p2l, pad_n);
        conv2_mfma_k<<<dim3(NB, 4), 256, 0, stream>>>(p1h, p1l, w2p, b2, p2h, p2l);
        conv3pool_k<<<NB, 256, 0, stream>>>(p2h, p2l, w3p, b3, feat, b0);
    }
    fc_k<<<Bfull, 128, 0, stream>>>(feat, fw1, fb1, fw2, fb2, out);
}

// Round 11
// 446.399 us; speedup vs baseline: 4.5603x; 1.0778x over previous
//
#include <hip/hip_runtime.h>
#include <cstddef>

typedef unsigned short ushort_t;
typedef unsigned uv4 __attribute__((ext_vector_type(4)));
typedef unsigned uv2 __attribute__((ext_vector_type(2)));
typedef float f32x4 __attribute__((ext_vector_type(4)));

// ---------------- problem constants ----------------
constexpr int Bfull = 512;
constexpr int F = 4, O = 10;

// per-image byte sizes (all 16B-aligned)
constexpr size_t TB_B  = (size_t)136 * 136 * 4 * 2;   // 147,968
constexpr size_t P1_B  = (size_t)35 * 35 * 32 * 2;    // 78,400 (each of h,l)
constexpr size_t P2_B  = (size_t)17 * 18 * 64 * 2;    // 39,168 (each of h,l)
constexpr size_t FEAT_B = (size_t)Bfull * 128 * 4;    // 262,144
constexpr size_t W1P_ELEMS = (size_t)7 * 4 * 16 * 32;        // 28672 ushort
constexpr size_t W2P_ELEMS = (size_t)25 * 2 * 64 * 32;       // 102400 ushort
constexpr size_t W3P_ELEMS = (size_t)9 * 2 * 2 * 128 * 32;   // 147456 ushort

__device__ __forceinline__ ushort_t f2bf_rne(float x) {
    unsigned u = __builtin_bit_cast(unsigned, x);
    unsigned r = (u + 0x7FFFu + ((u >> 16) & 1u)) >> 16;
    return (ushort_t)r;
}
__device__ __forceinline__ float bf2f(ushort_t b) {
    return __builtin_bit_cast(float, (unsigned)b << 16);
}

#define MFMA16(acc, a, b) \
    asm("v_mfma_f32_16x16x32_bf16 %0, %1, %2, %0" : "+v"(acc) : "v"(a), "v"(b))

// ---------------- rasterize -> padded bf16 [b][136r][136c][4ic] ----------------
__global__ __launch_bounds__(256) void rasterize_bf_k(const int* __restrict__ x,
                                                      ushort_t* __restrict__ tb, int b0) {
    int b_l = blockIdx.x;
    int rg  = blockIdx.y;             // row-group 0..7
    int b = b0 + b_l;
    __shared__ int pts[F][O][2];
    __shared__ int prm[F][24];
    int tid = threadIdx.x;
    if (tid < F * O * 2)
        ((int*)pts)[tid] = x[(size_t)b * F * O * 2 + tid];
    __syncthreads();
    if (tid < F) {
        int f = tid;
        int dX = 64 + pts[f][O - 1][0];
        int dY = 64 - pts[f][O - 1][1];
        prm[f][0] = dX; prm[f][1] = dY;
        prm[f][2] = dX >= 64 ? 64 : dX + 1; prm[f][3] = dX >= 64 ? dX - 1 : 64;
        prm[f][4] = dY >= 64 ? 64 : dY + 1; prm[f][5] = dY >= 64 ? dY - 1 : 64;
        for (int k = 0; k < O - 1; ++k) {
            prm[f][6 + k]  = (pts[f][k][0] + 64) % 127;
            prm[f][15 + k] = (64 - pts[f][k][1]) % 127;
        }
    }
    __syncthreads();
    ushort_t* outp = tb + (size_t)b_l * 136 * 136 * 4;
    int r0 = rg * 17;
    for (int i = tid; i < 17 * 136; i += 256) {
        int r = r0 + i / 136, c = i % 136;
        int y = r - 3, xx = c - 3;
        unsigned pack0 = 0, pack1 = 0;
        if (y >= 0 && y < 128 && xx >= 0 && xx < 128) {
            bool ctr9 = (y >= 63 && y <= 65 && xx >= 63 && xx <= 65);
            bool ctr1 = (y == 64 && xx == 64);
            #pragma unroll
            for (int f = 0; f < 4; ++f) {
                unsigned bf;
                if (ctr1) bf = 0x3F80u;
                else if (ctr9) bf = 0x3F00u;
                else {
                    int dX = prm[f][0];
                    bool mX = (xx >= prm[f][2]) && (xx <= prm[f][3]);
                    bool mY = (y >= prm[f][4]) && (y <= prm[f][5]);
                    bf = ((mX && y == 64) || (mY && xx == dX)) ? 0xBF80u : 0u;
                }
                if (f & 1) { if (f >> 1) pack1 |= bf << 16; else pack0 |= bf << 16; }
                else       { if (f >> 1) pack1 |= bf;       else pack0 |= bf; }
            }
        }
        uv2 pk; pk.x = pack0; pk.y = pack1;
        *(uv2*)(outp + ((size_t)r * 136 + c) * 4) = pk;
    }
    __syncthreads();
    if (tid < 4) {
        int f = tid;
        int r1 = r0 + 17;
        for (int k = 0; k < O - 1; ++k) {
            int a = prm[f][6 + k] + 3, bb = prm[f][15 + k] + 3;
            #pragma unroll
            for (int dy = -1; dy <= 1; ++dy) {
                int rr = bb + dy;
                if (rr >= r0 && rr < r1) {
                    ushort_t* rowp = outp + ((size_t)rr * 136 + a - 1) * 4 + f;
                    rowp[0] = 0x3F00u; rowp[4] = 0x3F00u; rowp[8] = 0x3F00u;
                }
            }
            if (bb >= r0 && bb < r1) outp[((size_t)bb * 136 + a) * 4 + f] = 0x3F80u;
        }
    }
}

// ---------------- prep_w1 ----------------
__global__ __launch_bounds__(256) void prep_w1_k(const float* __restrict__ w1,
                                                 ushort_t* __restrict__ w1p) {
    int idx = blockIdx.x * 256 + threadIdx.x;
    if (idx >= (int)W1P_ELEMS) return;
    int k = idx & 31, lr = (idx >> 5) & 15, slot = (idx >> 9) & 3, ky = idx >> 11;
    int hl = slot & 1, m = slot >> 1;
    int kx = k >> 2, ic = k & 3;
    int oc = m * 16 + lr;
    float w = (kx < 7) ? w1[((oc * 4 + ic) * 7 + ky) * 7 + kx] : 0.f;
    ushort_t h = f2bf_rne(w);
    w1p[idx] = hl ? f2bf_rne(w - bf2f(h)) : h;
}

// ---------------- conv1 + pool1 fused (LDS x-pool) ----------------
// grid (NB, 4); wave w computes conv rows yt*16+4w..+4 (5 rows, 1 redundant),
// row-pools into registers, writes [2 pool rows][64 cols][32 ch] f32 to LDS;
// after barrier, a simple indexed phase x-pools cols 2px..2px+2 and stores p1.
__global__ __launch_bounds__(256) void conv1pool_k(const ushort_t* __restrict__ tb,
                                                   const ushort_t* __restrict__ w1p,
                                                   const float* __restrict__ b1,
                                                   ushort_t* __restrict__ p1h,
                                                   ushort_t* __restrict__ p1l) {
    __shared__ float sP[8 * 64 * 33];   // [prow][col][ch], +1 pad on ch dim; 67,584 B
    int b_l = blockIdx.x;
    int yt  = blockIdx.y;
    int wave = threadIdx.x >> 6, lane = threadIdx.x & 63;
    int lr = lane & 15, lq = lane >> 4;
    const ushort_t* tbb = tb + (size_t)b_l * 136 * 136 * 4;
    int aoff = lr * 32 + lq * 8;
    float bias[2][4];
    #pragma unroll
    for (int m = 0; m < 2; ++m)
        #pragma unroll
        for (int j = 0; j < 4; ++j)
            bias[m][j] = b1[m * 16 + lq * 4 + j];
    int base = yt * 16 + wave * 4;

    f32x4 pacc[2][2][4];   // [pr][m][xt]; relu >= 0 so 0 is max-identity
    #pragma unroll
    for (int p = 0; p < 2; ++p)
        #pragma unroll
        for (int m = 0; m < 2; ++m)
            #pragma unroll
            for (int xt = 0; xt < 4; ++xt)
                pacc[p][m][xt] = (f32x4)0.f;

    #pragma unroll 1
    for (int rr = 0; rr < 5; ++rr) {
        int oy = base + rr; oy = oy > 63 ? 63 : oy;
        f32x4 acc[2][4];
        #pragma unroll
        for (int m = 0; m < 2; ++m)
            #pragma unroll
            for (int xt = 0; xt < 4; ++xt)
                acc[m][xt] = (f32x4)0.f;
        #pragma unroll
        for (int ky = 0; ky < 7; ++ky) {
            const ushort_t* wb = w1p + (size_t)ky * 2048;
            uv4 ah0 = *(const uv4*)(wb + aoff);
            uv4 al0 = *(const uv4*)(wb + 512 + aoff);
            uv4 ah1 = *(const uv4*)(wb + 1024 + aoff);
            uv4 al1 = *(const uv4*)(wb + 1536 + aoff);
            const ushort_t* rb = tbb + (size_t)(2 * oy + ky) * (136 * 4);
            #pragma unroll
            for (int xt = 0; xt < 4; ++xt) {
                uv4 bv = *(const uv4*)(rb + (size_t)(2 * (xt * 16 + lr) + 2 * lq) * 4);
                MFMA16(acc[0][xt], ah0, bv);
                MFMA16(acc[1][xt], ah1, bv);
                MFMA16(acc[0][xt], al0, bv);
                MFMA16(acc[1][xt], al1, bv);
            }
        }
        asm volatile("s_nop 7\n\ts_nop 7");
        #pragma unroll
        for (int m = 0; m < 2; ++m)
            #pragma unroll
            for (int xt = 0; xt < 4; ++xt)
                #pragma unroll
                for (int j = 0; j < 4; ++j) {
                    float v = fmaxf(acc[m][xt][j] + bias[m][j], 0.f);
                    if (rr <= 2) pacc[0][m][xt][j] = fmaxf(pacc[0][m][xt][j], v);
                    if (rr >= 2) pacc[1][m][xt][j] = fmaxf(pacc[1][m][xt][j], v);
                }
    }

    // write row-pooled values to LDS: prow = 2*wave + pr (block-local pool row)
    int prow0 = 2 * wave;
    #pragma unroll
    for (int pr = 0; pr < 2; ++pr)
        #pragma unroll
        for (int m = 0; m < 2; ++m)
            #pragma unroll
            for (int xt = 0; xt < 4; ++xt) {
                int col = xt * 16 + lr;
                float* dst = &sP[((prow0 + pr) * 64 + col) * 33 + m * 16 + lq * 4];
                #pragma unroll
                for (int j = 0; j < 4; ++j) dst[j] = pacc[pr][m][xt][j];
            }
    __syncthreads();

    // x-pool + hi/lo split + store interior p1 cells
    for (int i = threadIdx.x; i < 8 * 31 * 32; i += 256) {
        int ch = i & 31; int t = i >> 5;
        int px = t % 31; int r = t / 31;
        int py = yt * 8 + r;
        if (py > 30) continue;
        const float* s = &sP[((size_t)r * 64 + 2 * px) * 33 + ch];
        float v = fmaxf(fmaxf(s[0], s[33]), s[66]);
        ushort_t h = f2bf_rne(v);
        size_t addr = (((size_t)b_l * 35 + py + 2) * 35 + px + 2) * 32 + ch;
        p1h[addr] = h;
        p1l[addr] = f2bf_rne(v - bf2f(h));
    }
}

// ---------------- prep_w2 ----------------
__global__ __launch_bounds__(256) void prep_w2_k(const float* __restrict__ w2,
                                                 ushort_t* __restrict__ w2p) {
    int idx = blockIdx.x * 256 + threadIdx.x;
    if (idx >= 25 * 64 * 32) return;
    int ic = idx & 31, oc = (idx >> 5) & 63, kk = idx >> 11;
    float w = w2[(size_t)(oc * 32 + ic) * 25 + kk];
    ushort_t h = f2bf_rne(w);
    w2p[(size_t)kk * 4096 + (idx & 2047)] = h;
    w2p[(size_t)kk * 4096 + 2048 + (idx & 2047)] = f2bf_rne(w - bf2f(h));
}

// ---------------- conv2 MFMA + LDS-staged B (pad-zeroing) + fused bias/relu/pool2 ----------------
__global__ __launch_bounds__(256) void conv2_mfma_k(const ushort_t* __restrict__ p1h,
                                                    const ushort_t* __restrict__ p1l,
                                                    const ushort_t* __restrict__ w2p,
                                                    const float* __restrict__ b2,
                                                    ushort_t* __restrict__ p2h,
                                                    ushort_t* __restrict__ p2l) {
    __shared__ ushort_t sB[2][13440];   // [plane][r<12][pc<35][k<32], swizzled k-chunk
    int b_l = blockIdx.x;
    int yt  = blockIdx.y;
    int y0 = yt * 8;
    int nrows = (35 - y0) < 12 ? (35 - y0) : 12;   // 12,12,12,11
    int tid = threadIdx.x;

    {
        int nchunks = nrows * 35 * 4;
        const ushort_t* src0 = p1h + (size_t)b_l * 35 * 1120 + (size_t)y0 * 1120;
        const ushort_t* src1 = p1l + (size_t)b_l * 35 * 1120 + (size_t)y0 * 1120;
        for (int c = tid; c < 2 * nchunks; c += 256) {
            int p = c >= nchunks;
            int cc = p ? c - nchunks : c;
            int lqi = cc & 3;
            int pc = (cc >> 2) % 35;
            int r = cc / 140;
            int pr_g = y0 + r;
            bool inb = (pr_g >= 2 && pr_g <= 32 && pc >= 2 && pc <= 32);
            const ushort_t* s = p ? src1 : src0;
            uv4 v = *(const uv4*)(s + (size_t)r * 1120 + pc * 32 + lqi * 8);
            if (!inb) v = (uv4)0u;     // p1 pads are never written: zero-fill here
            int swz = lqi ^ ((pc >> 1) & 3);
            *(uv4*)(&sB[p][(r * 35 + pc) * 32 + swz * 8]) = v;
        }
    }
    __syncthreads();

    int wave = threadIdx.x >> 6;
    int lane = threadIdx.x & 63;
    int wm = wave & 1, wy = wave >> 1;
    int oc0 = wm * 32;
    int lr = lane & 15, lq = lane >> 4;
    int rclip = 34 - y0;

    f32x4 acc[4][2][2];
    #pragma unroll
    for (int y = 0; y < 4; ++y)
        #pragma unroll
        for (int m = 0; m < 2; ++m)
            #pragma unroll
            for (int n = 0; n < 2; ++n)
                acc[y][m][n] = (f32x4)0.f;

    int aoff = (oc0 + lr) * 32 + lq * 8;

    #pragma unroll 1
    for (int kk = 0; kk < 25; ++kk) {
        int ky = kk / 5, kx = kk % 5;
        const ushort_t* wb = w2p + (size_t)kk * 4096;
        uv4 ah0 = *(const uv4*)(wb + aoff);
        uv4 ah1 = *(const uv4*)(wb + aoff + 512);
        uv4 al0 = *(const uv4*)(wb + 2048 + aoff);
        uv4 al1 = *(const uv4*)(wb + 2048 + aoff + 512);
        int pcc[2];
        #pragma unroll
        for (int xt = 0; xt < 2; ++xt) {
            int pc = xt * 16 + lr + kx; pc = pc > 34 ? 34 : pc;
            pcc[xt] = pc * 32 + (lq ^ ((pc >> 1) & 3)) * 8;
        }
        #pragma unroll
        for (int y = 0; y < 4; ++y) {
            int r = wy * 4 + y + ky; r = r > rclip ? rclip : r;
            int rbase = r * 1120;
            #pragma unroll
            for (int xt = 0; xt < 2; ++xt) {
                int off = rbase + pcc[xt];
                uv4 bh = *(const uv4*)(&sB[0][off]);
                uv4 bl = *(const uv4*)(&sB[1][off]);
                MFMA16(acc[y][0][xt], ah0, bh);
                MFMA16(acc[y][1][xt], ah1, bh);
                MFMA16(acc[y][0][xt], ah0, bl);
                MFMA16(acc[y][1][xt], ah1, bl);
                MFMA16(acc[y][0][xt], al0, bh);
                MFMA16(acc[y][1][xt], al1, bh);
            }
        }
    }
    asm volatile("s_nop 7\n\ts_nop 7");

    float bias[2][4];
    #pragma unroll
    for (int m = 0; m < 2; ++m)
        #pragma unroll
        for (int j = 0; j < 4; ++j)
            bias[m][j] = b2[oc0 + m * 16 + lq * 4 + j];

    int ybase = y0 + wy * 4;
    #pragma unroll
    for (int yp = 0; yp < 2; ++yp) {
        int yy = ybase + 2 * yp;
        if (yy + 1 > 30) continue;   // wave-uniform
        int py = yy >> 1;
        #pragma unroll
        for (int m = 0; m < 2; ++m)
            #pragma unroll
            for (int xt = 0; xt < 2; ++xt)
                #pragma unroll
                for (int j = 0; j < 4; ++j) {
                    float v = fmaxf(acc[2 * yp][m][xt][j], acc[2 * yp + 1][m][xt][j]);
                    float o = __shfl_xor(v, 1, 64);
                    v = fmaxf(fmaxf(v, o) + bias[m][j], 0.f);
                    int px = xt * 8 + (lr >> 1);
                    if (!(lane & 1) && px < 15) {
                        int oc = oc0 + m * 16 + lq * 4 + j;
                        size_t oo = (((size_t)b_l * 17 + py + 1) * 18 + px + 1) * 64 + oc;
                        ushort_t h = f2bf_rne(v);
                        p2h[oo] = h;
                        p2l[oo] = f2bf_rne(v - bf2f(h));
                    }
                }
    }
}

// ---------------- prep_w3 ----------------
__global__ __launch_bounds__(256) void prep_w3_k(const float* __restrict__ w3,
                                                 ushort_t* __restrict__ w3p) {
    int idx = blockIdx.x * 256 + threadIdx.x;
    if (idx >= (int)W3P_ELEMS) return;
    int kk = idx & 31, oc = (idx >> 5) & 127, hl = (idx >> 12) & 1, ks = (idx >> 13) & 1, kxy = idx >> 14;
    int ky = kxy / 3, kx = kxy % 3;
    int ic = ks * 32 + kk;
    float w = w3[((size_t)(oc * 64 + ic) * 3 + ky) * 3 + kx];
    ushort_t h = f2bf_rne(w);
    w3p[idx] = hl ? f2bf_rne(w - bf2f(h)) : h;
}

// ---------------- conv3 + pool3 + mean, fused -> feat ----------------
// p2 pads are never written in global: staging zero-fills pad cells.
__global__ __launch_bounds__(256) void conv3pool_k(const ushort_t* __restrict__ p2h,
                                                   const ushort_t* __restrict__ p2l,
                                                   const ushort_t* __restrict__ w3p,
                                                   const float* __restrict__ b3,
                                                   float* __restrict__ feat, int b0) {
    __shared__ ushort_t sB[2][19584];   // [plane][rc<306][64], 16B slots swizzled by c&7
    int b_l = blockIdx.x;
    int tid = threadIdx.x;
    {
        const ushort_t* s0 = p2h + (size_t)b_l * 19584;
        const ushort_t* s1 = p2l + (size_t)b_l * 19584;
        for (int ccg = tid; ccg < 4896; ccg += 256) {
            int p = ccg >= 2448;
            int cc = p ? ccg - 2448 : ccg;
            int rc = cc >> 3, slot = cc & 7;
            int r = rc / 18, c = rc % 18;
            bool pad = (r == 0 || r == 16 || c == 0 || c >= 16);
            uv4 v = *(const uv4*)((p ? s1 : s0) + (size_t)cc * 8);
            if (pad) v = (uv4)0u;
            *(uv4*)(&sB[p][rc * 64 + (slot ^ (c & 7)) * 8]) = v;
        }
    }
    __syncthreads();
    int wave = tid >> 6, lane = tid & 63;
    int lr = lane & 15, lq = lane >> 4;
    int oc0 = wave * 32;
    float bias[2][4];
    #pragma unroll
    for (int m = 0; m < 2; ++m)
        #pragma unroll
        for (int j = 0; j < 4; ++j)
            bias[m][j] = b3[oc0 + m * 16 + lq * 4 + j];
    f32x4 fsum[2];
    fsum[0] = (f32x4)0.f; fsum[1] = (f32x4)0.f;

    int cl = lr;
    #pragma unroll 1
    for (int pr = 0; pr < 7; ++pr) {
        f32x4 acc[2][2];
        #pragma unroll
        for (int rr = 0; rr < 2; ++rr) { acc[rr][0] = (f32x4)0.f; acc[rr][1] = (f32x4)0.f; }
        #pragma unroll 1
        for (int ky = 0; ky < 3; ++ky)
            #pragma unroll 1
            for (int kx = 0; kx < 3; ++kx) {
                int c = cl + kx;
                int cs = c & 7;
                #pragma unroll
                for (int ks = 0; ks < 2; ++ks) {
                    const ushort_t* wb = w3p + (size_t)(((ky * 3 + kx) * 2 + ks) * 2) * 4096;
                    uv4 ah0 = *(const uv4*)(wb + (oc0 + lr) * 32 + lq * 8);
                    uv4 ah1 = *(const uv4*)(wb + (oc0 + 16 + lr) * 32 + lq * 8);
                    uv4 al0 = *(const uv4*)(wb + 4096 + (oc0 + lr) * 32 + lq * 8);
                    uv4 al1 = *(const uv4*)(wb + 4096 + (oc0 + 16 + lr) * 32 + lq * 8);
                    int slotk = ((ks << 2) | lq) ^ cs;
                    #pragma unroll
                    for (int rr = 0; rr < 2; ++rr) {
                        int r = 2 * pr + rr + ky;
                        int off = (r * 18 + c) * 64 + slotk * 8;
                        uv4 bh = *(const uv4*)(&sB[0][off]);
                        uv4 bl = *(const uv4*)(&sB[1][off]);
                        MFMA16(acc[rr][0], ah0, bh);
                        MFMA16(acc[rr][1], ah1, bh);
                        MFMA16(acc[rr][0], ah0, bl);
                        MFMA16(acc[rr][1], ah1, bl);
                        MFMA16(acc[rr][0], al0, bh);
                        MFMA16(acc[rr][1], al1, bh);
                    }
                }
            }
        asm volatile("s_nop 7\n\ts_nop 7");
        #pragma unroll
        for (int m = 0; m < 2; ++m)
            #pragma unroll
            for (int j = 0; j < 4; ++j) {
                float v0 = fmaxf(acc[0][m][j] + bias[m][j], 0.f);
                float v1 = fmaxf(acc[1][m][j] + bias[m][j], 0.f);
                float vm = fmaxf(v0, v1);
                float o = __shfl_xor(vm, 1, 64);
                float pooled = fmaxf(vm, o);
                if (lr < 14) fsum[m][j] += pooled;
            }
    }
    #pragma unroll
    for (int m = 0; m < 2; ++m)
        #pragma unroll
        for (int j = 0; j < 4; ++j) {
            float t = fsum[m][j];
            t += __shfl_xor(t, 1, 64);
            t += __shfl_xor(t, 2, 64);
            t += __shfl_xor(t, 4, 64);
            t += __shfl_xor(t, 8, 64);
            if (lr == 0)
                feat[(size_t)(b0 + b_l) * 128 + oc0 + m * 16 + lq * 4 + j] = t * (1.f / 98.f);
        }
}

// ---------------- fc1 (relu) + fc2 ----------------
__global__ __launch_bounds__(128) void fc_k(const float* __restrict__ feat,
                                            const float* __restrict__ fw1,
                                            const float* __restrict__ fb1,
                                            const float* __restrict__ fw2,
                                            const float* __restrict__ fb2,
                                            float* __restrict__ out) {
    __shared__ float sF[128];
    __shared__ float sH[128];
    int b = blockIdx.x, tid = threadIdx.x;
    sF[tid] = feat[(size_t)b * 128 + tid];
    __syncthreads();
    const float4* wrow = (const float4*)(fw1 + (size_t)tid * 128);
    float s = fb1[tid];
    #pragma unroll
    for (int i = 0; i < 32; ++i) {
        float4 w = wrow[i];
        s = fmaf(w.x, sF[4 * i], s);
        s = fmaf(w.y, sF[4 * i + 1], s);
        s = fmaf(w.z, sF[4 * i + 2], s);
        s = fmaf(w.w, sF[4 * i + 3], s);
    }
    sH[tid] = fmaxf(s, 0.f);
    __syncthreads();
    if (tid < 5) {
        const float* w2r = fw2 + (size_t)tid * 128;
        float s2 = fb2[tid];
        for (int i = 0; i < 128; ++i) s2 = fmaf(w2r[i], sH[i], s2);
        out[(size_t)b * 5 + tid] = s2;
    }
}

// ---------------- launch ----------------
extern "C" void kernel_launch(void* const* d_in, const int* in_sizes, int n_in,
                              void* d_out, int out_size, void* d_ws, size_t ws_size,
                              hipStream_t stream) {
    const int*   x   = (const int*)d_in[0];
    const float* w1  = (const float*)d_in[1];
    const float* b1  = (const float*)d_in[2];
    const float* w2  = (const float*)d_in[3];
    const float* b2  = (const float*)d_in[4];
    const float* w3  = (const float*)d_in[5];
    const float* b3  = (const float*)d_in[6];
    const float* fw1 = (const float*)d_in[7];
    const float* fb1 = (const float*)d_in[8];
    const float* fw2 = (const float*)d_in[9];
    const float* fb2 = (const float*)d_in[10];
    float* out = (float*)d_out;

    const size_t per_img = TB_B + 2 * P1_B + 2 * P2_B;   // 383,104 B
    const size_t fixed_b = FEAT_B + (W1P_ELEMS + W2P_ELEMS + W3P_ELEMS) * 2 + 1024;
    int NB = Bfull;
    while (NB > 128 && fixed_b + per_img * (size_t)NB > ws_size) NB >>= 1;

    char* base = (char*)d_ws;
    float* feat = (float*)base;                         base += FEAT_B;
    ushort_t* tb  = (ushort_t*)base;                    base += (size_t)NB * TB_B;
    ushort_t* p1h = (ushort_t*)base;                    base += (size_t)NB * P1_B;
    ushort_t* p1l = (ushort_t*)base;                    base += (size_t)NB * P1_B;
    ushort_t* p2h = (ushort_t*)base;                    base += (size_t)NB * P2_B;
    ushort_t* p2l = (ushort_t*)base;                    base += (size_t)NB * P2_B;
    ushort_t* w1p = (ushort_t*)base;                    base += W1P_ELEMS * 2;
    ushort_t* w2p = (ushort_t*)base;                    base += W2P_ELEMS * 2;
    ushort_t* w3p = (ushort_t*)base;

    prep_w1_k<<<((int)W1P_ELEMS + 255) / 256, 256, 0, stream>>>(w1, w1p);
    prep_w2_k<<<(25 * 64 * 32 + 255) / 256, 256, 0, stream>>>(w2, w2p);
    prep_w3_k<<<((int)W3P_ELEMS + 255) / 256, 256, 0, stream>>>(w3, w3p);

    const int nchunk = Bfull / NB;
    for (int ch = 0; ch < nchunk; ++ch) {
        int b0 = ch * NB;
        rasterize_bf_k<<<dim3(NB, 8), 256, 0, stream>>>(x, tb, b0);
        conv1pool_k<<<dim3(NB, 4), 256, 0, stream>>>(tb, w1p, b1, p1h, p1l);
        conv2_mfma_k<<<dim3(NB, 4), 256, 0, stream>>>(p1h, p1l, w2p, b2, p2h, p2l);
        conv3pool_k<<<NB, 256, 0, stream>>>(p2h, p2l, w3p, b3, feat, b0);
    }
    fc_k<<<Bfull, 128, 0, stream>>>(feat, fw1, fb1, fw2, fb2, out);
}